// Round 14
// baseline (130.572 us; speedup 1.0000x reference)
//
#include <hip/hip_runtime.h>
#include <hip/hip_bf16.h>

// Problem constants
#define BH 96      // B*H
#define TOK 2048   // B*N
#define THW 24576  // B*H*N

typedef unsigned short ushort_t;
typedef __attribute__((ext_vector_type(8))) short short8;
typedef __attribute__((ext_vector_type(4))) float f32x4;

static __device__ __forceinline__ float bf2f(ushort_t u){
  union { unsigned int i; float f; } t; t.i = ((unsigned int)u)<<16; return t.f;
}
static __device__ __forceinline__ ushort_t f2bf(float f){
  union { float f; unsigned int i; } t; t.f = f;
  unsigned int u = t.i;
  return (ushort_t)((u + 0x7fffu + ((u>>16)&1u)) >> 16);
}
static __device__ __forceinline__ short8 pack8(f32x4 a, f32x4 b){
  short8 r;
  #pragma unroll
  for (int j=0;j<4;++j){ r[j]=(short)f2bf(a[j]); r[4+j]=(short)f2bf(b[j]); }
  return r;
}
static __device__ __forceinline__ float gelu_exact(float x){
  return 0.5f*x*(1.0f + erff(x*0.70710678118654752f));
}
// 8 f32 scaled by s -> bf16x8 (RNE via v_cvt_pk_bf16_f32)
static __device__ __forceinline__ short8 mulpack8(const float* f, float s){
  union { short8 s8; unsigned int u[4]; } r;
  #pragma unroll
  for (int j=0;j<4;++j){
    float2 p2; p2.x = f[2*j]*s; p2.y = f[2*j+1]*s;
    __hip_bfloat162 p = __float22bfloat162_rn(p2);
    r.u[j] = *(unsigned int*)&p;
  }
  return r.s8;
}
// async global->LDS, 16B per lane; LDS dest = uniform base + lane*16
static __device__ __forceinline__ void glds16(const ushort_t* g, ushort_t* l){
  __builtin_amdgcn_global_load_lds(
      (const __attribute__((address_space(1))) unsigned int*)g,
      (__attribute__((address_space(3))) unsigned int*)l, 16, 0, 0);
}

// ---------------------------------------------------------------------------
// K0: unified bf16 pack. Regions (elem offsets, all /8):
//  [0, 1572864)            x        -> xb
//  [1572864, 4521984)      wqkv/wl/wg -> wb
//  [4521984, 5111808)      w_proj   -> wpb
//  [5111808, 5378048)      w_g,w_bg -> wgb
__global__ __launch_bounds__(256) void k_pack(
    const float* __restrict__ x, const float* __restrict__ w_qkv,
    const float* __restrict__ w_local, const float* __restrict__ w_global,
    const float* __restrict__ w_proj, const float* __restrict__ w_g,
    const float* __restrict__ w_bg,
    ushort_t* __restrict__ xb, ushort_t* __restrict__ wb,
    ushort_t* __restrict__ wpb, ushort_t* __restrict__ wgb)
{
  size_t i = ((size_t)blockIdx.x*256 + threadIdx.x)*8;
  const float* src; ushort_t* dst; size_t off;
  if (i < 1572864){ src = x; dst = xb; off = i; }
  else if (i < 4521984){
    size_t j = i - 1572864; dst = wb; off = j;
    if (j < 1769472)      src = w_qkv;
    else if (j < 2359296) src = w_local - 1769472;
    else                  src = w_global - 2359296;
  }
  else if (i < 5111808){ off = i - 4521984; src = w_proj; dst = wpb; }
  else {
    size_t j = i - 5111808; dst = wgb; off = j;
    src = (j < 262144) ? w_g : (w_bg - 262144);
  }
  f32x4 a = *(const f32x4*)(src + off);
  f32x4 b = *(const f32x4*)(src + off + 4);
  *(short8*)(dst + off) = pack8(a, b);
}

// ---------------------------------------------------------------------------
// K1 v7: bf16 GEMM Y = xb @ wb^T + bias (M=2048, N=3840, K=768)
// 128x64 tile, BK=32, DOUBLE-BUFFERED at 24KB total (same LDS as v4 single):
// As[2][128*32]=16KB + Bs[2][64*32]=8KB. Prefetch next K-step before compute;
// 1 barrier/step. Swizzle: outproj-template (free 2-way).
__global__ __launch_bounds__(256) void k_proj(
    const ushort_t* __restrict__ xb, const ushort_t* __restrict__ wb,
    const float* __restrict__ b_qkv, const float* __restrict__ b_local,
    const float* __restrict__ b_global,
    ushort_t* __restrict__ qb, ushort_t* __restrict__ kb, ushort_t* __restrict__ vb,
    ushort_t* __restrict__ lib, ushort_t* __restrict__ gib)
{
  __shared__ ushort_t As[2][128*32];   // 16 KB
  __shared__ ushort_t Bs[2][64*32];    //  8 KB
  const int n0 = blockIdx.x*64;
  const int m0 = blockIdx.y*128;
  const int t = threadIdx.x, w = t>>6, l = t&63;
  const int wm = (w>>1)*64, wn = (w&1)*32;
  const int lr = l&15, lk = l>>4;               // lk 0..3
  const int srow = l>>2;                        // 0..15 within 16-row chunk
  const int scol = ((l&3) ^ ((l>>3)&3)) << 3;   // inverse-swizzled elem col
  const int rdoff = (lk ^ ((lr>>1)&3)) << 3;    // read-side swizzle
  f32x4 acc[4][2];
  #pragma unroll
  for (int a=0;a<4;++a){ acc[a][0]=(f32x4){0,0,0,0}; acc[a][1]=(f32x4){0,0,0,0}; }

  auto STAGE = [&](int bsel, int k0){
    // A: wave w stages 16-row chunks {w, w+4}; B: chunk w
    glds16(xb + (size_t)(m0      + w*16 + srow)*768 + k0 + scol, &As[bsel][(     w*16)*32]);
    glds16(xb + (size_t)(m0 + 64 + w*16 + srow)*768 + k0 + scol, &As[bsel][(64 + w*16)*32]);
    glds16(wb + (size_t)(n0      + w*16 + srow)*768 + k0 + scol, &Bs[bsel][(     w*16)*32]);
  };

  STAGE(0, 0);
  __syncthreads();                      // drains vmcnt -> buf0 ready

  for (int ts=0; ts<24; ++ts){
    const int cur = ts & 1;
    if (ts < 23) STAGE(cur^1, (ts+1)*32);   // prefetch flies during compute
    const ushort_t* Ab = &As[cur][0];
    const ushort_t* Bb = &Bs[cur][0];
    short8 af[4], bf[2];
    #pragma unroll
    for (int fm=0; fm<4; ++fm){
      int R = wm + fm*16 + lr;
      af[fm] = *(const short8*)(Ab + R*32 + rdoff);
    }
    #pragma unroll
    for (int fn=0; fn<2; ++fn){
      int R = wn + fn*16 + lr;
      bf[fn] = *(const short8*)(Bb + R*32 + rdoff);
    }
    #pragma unroll
    for (int fm=0; fm<4; ++fm)
      #pragma unroll
      for (int fn=0; fn<2; ++fn)
        acc[fm][fn] = __builtin_amdgcn_mfma_f32_16x16x32_bf16(af[fm], bf[fn], acc[fm][fn],0,0,0);
    __syncthreads();   // drains lgkm (reads done) + vmcnt (prefetch landed)
  }

  #pragma unroll
  for (int fm=0; fm<4; ++fm){
    #pragma unroll
    for (int fn=0; fn<2; ++fn){
      #pragma unroll
      for (int r=0; r<4; ++r){
        int grow = m0 + wm + fm*16 + lk*4 + r;
        int colg = n0 + wn + fn*16 + lr;
        int b = grow>>8, n = grow&255;
        if (colg < 2304){
          float val = acc[fm][fn][r] + b_qkv[colg];
          int s = colg/768, rr = colg - s*768;
          int h = rr>>6, d = rr&63;
          size_t idx = ((size_t)(b*12+h)*256 + n)*64 + d;
          if (s==0)      qb[idx] = f2bf(val*0.125f);
          else if (s==1) kb[idx] = f2bf(val);
          else           vb[idx] = f2bf(val);
        } else if (colg < 3072){
          int cl = colg - 2304;
          float val = acc[fm][fn][r] + b_local[cl];
          int h = cl>>6, d = cl&63;
          lib[((size_t)(b*12+h)*256 + n)*64 + d] = f2bf(gelu_exact(val));
        } else {
          int cl = colg - 3072;
          float val = acc[fm][fn][r] + b_global[cl];
          int h = cl>>6, d = cl&63;
          gib[((size_t)(b*12+h)*256 + n)*64 + d] = f2bf(gelu_exact(val));
        }
      }
    }
  }
}

// ---------------------------------------------------------------------------
// K2: transpose [bh][m][e] -> [bh][e][m] for v and gi
__global__ __launch_bounds__(256) void k_transpose(
    const ushort_t* __restrict__ vb, const ushort_t* __restrict__ gib,
    ushort_t* __restrict__ vT, ushort_t* __restrict__ giT)
{
  int bh = blockIdx.x;
  const ushort_t* src = blockIdx.y ? gib : vb;
  ushort_t* dst       = blockIdx.y ? giT : vT;
  __shared__ ushort_t tile[256*72];
  int t = threadIdx.x;
  for (int i=t; i<2048; i+=256){
    int m = i>>3, e0 = (i&7)*8;
    *(short8*)(tile + m*72 + e0) =
      *(const short8*)(src + ((size_t)bh*256 + m)*64 + e0);
  }
  __syncthreads();
  for (int i=t; i<2048; i+=256){
    int e = i>>5, m0 = (i&31)*8;
    short8 v;
    #pragma unroll
    for (int j=0;j<8;++j) v[j] = (short)tile[(m0+j)*72 + e];
    *(short8*)(dst + ((size_t)bh*64 + e)*256 + m0) = v;
  }
}

// ---------------------------------------------------------------------------
// K3a v4: col-split x2 for occupancy. Grid (96,8): block = 32 rows.
__global__ __launch_bounds__(256) void k_logits(
    const ushort_t* __restrict__ qb, const ushort_t* __restrict__ kb,
    ushort_t* __restrict__ S, float* __restrict__ rmaxb, float* __restrict__ rsumb,
    float* __restrict__ colpm, float* __restrict__ colps)
{
  __shared__ float lpm[2][256], lps[2][256];   // [rg][ch*128+col]
  __shared__ float rpm[2][32], rps[2][32];     // [ch][row-in-block]
  int bh = blockIdx.x, n0 = blockIdx.y*32;
  int t = threadIdx.x, w = t>>6, l = t&63;
  int rg = w&1, ch = w>>1;
  int lr = l&15, lk = (l>>4)*8;
  int row = n0 + rg*16 + lr;
  const ushort_t* qp = qb + ((size_t)bh*256 + row)*64 + lk;
  short8 a0 = *(const short8*)(qp);
  short8 a1 = *(const short8*)(qp + 32);
  f32x4 acc[8];
  #pragma unroll
  for (int f=0; f<8; ++f) acc[f] = (f32x4){0,0,0,0};
  #pragma unroll
  for (int f=0; f<8; ++f){
    int col = ch*128 + f*16 + lr;
    const ushort_t* kp = kb + ((size_t)bh*256 + col)*64 + lk;
    short8 b0 = *(const short8*)(kp);
    short8 b1 = *(const short8*)(kp + 32);
    acc[f] = __builtin_amdgcn_mfma_f32_16x16x32_bf16(a0,b0,acc[f],0,0,0);
    acc[f] = __builtin_amdgcn_mfma_f32_16x16x32_bf16(a1,b1,acc[f],0,0,0);
  }
  #pragma unroll
  for (int r=0; r<4; ++r){
    int nl = rg*16 + (l>>4)*4 + r;            // row within block
    float mx = acc[0][r];
    #pragma unroll
    for (int f=1; f<8; ++f) mx = fmaxf(mx, acc[f][r]);
    mx = fmaxf(mx, __shfl_xor(mx, 1));
    mx = fmaxf(mx, __shfl_xor(mx, 2));
    mx = fmaxf(mx, __shfl_xor(mx, 4));
    mx = fmaxf(mx, __shfl_xor(mx, 8));
    float sm = 0.f;
    #pragma unroll
    for (int f=0; f<8; ++f) sm += __expf(acc[f][r] - mx);
    sm += __shfl_xor(sm, 1);
    sm += __shfl_xor(sm, 2);
    sm += __shfl_xor(sm, 4);
    sm += __shfl_xor(sm, 8);
    #pragma unroll
    for (int f=0; f<8; ++f)
      S[((size_t)bh*256 + n0 + nl)*256 + ch*128 + f*16 + lr] = f2bf(acc[f][r]);
    if (lr == 0){ rpm[ch][nl] = mx; rps[ch][nl] = sm; }
  }
  #pragma unroll
  for (int f=0; f<8; ++f){
    float pm = fmaxf(fmaxf(acc[f][0],acc[f][1]), fmaxf(acc[f][2],acc[f][3]));
    float ps = __expf(acc[f][0]-pm) + __expf(acc[f][1]-pm)
             + __expf(acc[f][2]-pm) + __expf(acc[f][3]-pm);
    #pragma unroll
    for (int m=16; m<64; m<<=1){
      float om = __shfl_xor(pm, m);
      float os = __shfl_xor(ps, m);
      float nm = fmaxf(pm, om);
      ps = ps*__expf(pm-nm) + os*__expf(om-nm);
      pm = nm;
    }
    if (l < 16){ lpm[rg][ch*128 + f*16 + lr] = pm; lps[rg][ch*128 + f*16 + lr] = ps; }
  }
  __syncthreads();
  if (t < 32){
    float M = rpm[0][t], Sm = rps[0][t];
    float om = rpm[1][t], os = rps[1][t];
    float nm = fmaxf(M, om);
    Sm = Sm*__expf(M-nm) + os*__expf(om-nm);
    rmaxb[bh*256 + n0 + t] = nm;
    rsumb[bh*256 + n0 + t] = Sm;
  }
  {
    float M = lpm[0][t], Sm = lps[0][t];
    float om = lpm[1][t], os = lps[1][t];
    float nm = fmaxf(M, om);
    Sm = Sm*__expf(M-nm) + os*__expf(om-nm);
    colpm[((size_t)bh*8 + blockIdx.y)*256 + t] = nm;
    colps[((size_t)bh*8 + blockIdx.y)*256 + t] = Sm;
  }
}

// ---------------------------------------------------------------------------
// K3c v4: kk-split x2 in-block + exp-factoring. Grid (96,8): block = 32 rows.
__global__ __launch_bounds__(256) void k_attnmm(
    const ushort_t* __restrict__ S,
    const float* __restrict__ rmaxb, const float* __restrict__ rsumb,
    const float* __restrict__ colpm, const float* __restrict__ colps,
    const ushort_t* __restrict__ vT, const ushort_t* __restrict__ giT,
    ushort_t* __restrict__ gsb, float* __restrict__ saf)
{
  __shared__ float ec_s[256];
  __shared__ float red[2][64][32];   // [rg][lane][8 x f32x4], XOR-swizzled
  int bh = blockIdx.x, n0 = blockIdx.y*32;
  int b = bh/12, h = bh - b*12;
  int t = threadIdx.x, w = t>>6, l = t&63;
  int rg = w&1, kh = w>>1;
  int lr = l&15;
  {
    const float* pm = colpm + (size_t)bh*2048;
    const float* ps = colps + (size_t)bh*2048;
    float M = pm[t], Ssum = ps[t];
    #pragma unroll
    for (int k=1; k<8; ++k){
      float om = pm[k*256+t], os = ps[k*256+t];
      float nm = fmaxf(M, om);
      Ssum = Ssum*__expf(M-nm) + os*__expf(om-nm);
      M = nm;
    }
    ec_s[t] = __expf(-M)/Ssum;
  }
  __syncthreads();
  int n = n0 + rg*16 + lr;   // A-fragment row
  float rmx = rmaxb[bh*256 + n];
  float er  = __expf(rmx);
  f32x4 asa[4], ags[4];
  #pragma unroll
  for (int fn=0; fn<4; ++fn){ asa[fn]=(f32x4){0,0,0,0}; ags[fn]=(f32x4){0,0,0,0}; }
  #pragma unroll
  for (int kq=0; kq<4; ++kq){
    int kk = kh*4 + kq;
    int mbase = kk*32 + (l>>4)*8;
    short8 sv = *(const short8*)(S + ((size_t)bh*256 + n)*256 + mbase);
    f32x4 ec_lo = *(const f32x4*)(ec_s + mbase);
    f32x4 ec_hi = *(const f32x4*)(ec_s + mbase + 4);
    short8 a_at, a_rat;
    #pragma unroll
    for (int j=0;j<4;++j){
      float e0 = __expf(bf2f((ushort_t)sv[j])   - rmx);
      float e1 = __expf(bf2f((ushort_t)sv[j+4]) - rmx);
      a_at[j]    = (short)f2bf(e0);
      a_at[j+4]  = (short)f2bf(e1);
      a_rat[j]   = (short)f2bf(e0 * er * ec_lo[j]);
      a_rat[j+4] = (short)f2bf(e1 * er * ec_hi[j]);
    }
    #pragma unroll
    for (int fn=0; fn<4; ++fn){
      int e = fn*16 + lr;
      short8 bv = *(const short8*)(vT  + ((size_t)bh*64 + e)*256 + mbase);
      short8 bg = *(const short8*)(giT + ((size_t)bh*64 + e)*256 + mbase);
      asa[fn] = __builtin_amdgcn_mfma_f32_16x16x32_bf16(a_at,  bv, asa[fn],0,0,0);
      ags[fn] = __builtin_amdgcn_mfma_f32_16x16x32_bf16(a_rat, bg, ags[fn],0,0,0);
    }
  }
  if (kh == 1){
    float* rp = &red[rg][l][0];
    #pragma unroll
    for (int fn=0; fn<4; ++fn){
      *(f32x4*)((char*)rp + (((2*fn)   ^ (l&7))*16)) = asa[fn];
      *(f32x4*)((char*)rp + (((2*fn+1) ^ (l&7))*16)) = ags[fn];
    }
  }
  __syncthreads();
  if (kh == 0){
    const float* rp = &red[rg][l][0];
    #pragma unroll
    for (int fn=0; fn<4; ++fn){
      f32x4 oa = *(const f32x4*)((const char*)rp + (((2*fn)   ^ (l&7))*16));
      f32x4 og = *(const f32x4*)((const char*)rp + (((2*fn+1) ^ (l&7))*16));
      asa[fn] += oa; ags[fn] += og;
    }
    #pragma unroll
    for (int r=0; r<4; ++r){
      int nr = n0 + rg*16 + (l>>4)*4 + r;
      float rinv = 1.0f / rsumb[bh*256 + nr];
      #pragma unroll
      for (int fn=0; fn<4; ++fn){
        int e = fn*16 + lr;
        saf[((size_t)(b*256 + nr))*768 + h*64 + e] = asa[fn][r] * rinv;
        gsb[((size_t)bh*256 + nr)*64 + e] = f2bf(ags[fn][r]);
      }
    }
  }
}

// ---------------------------------------------------------------------------
// K4 v3: K-split x4; partials -> isap[s]
__global__ __launch_bounds__(256) void k_isa(
    const ushort_t* __restrict__ lib, const ushort_t* __restrict__ gib,
    const ushort_t* __restrict__ gsb, const ushort_t* __restrict__ wgb,
    float* __restrict__ isap)
{
  __shared__ char smem[32768];   // 2 x 16KB granule buffers
  const int t = threadIdx.x, w = t>>6, l = t&63;
  const int lr = l&15, lk = l>>4;          // lk in 0..3
  const int t0 = blockIdx.x*128 + w*32;    // wave's first token
  const int s  = blockIdx.y;               // K-split 0..3
  const int d0 = s*16;
  const int inrow = lk*16;

  float  gif[2][2][8];
  short8 gsf[2][2];
  #pragma unroll
  for (int mt=0; mt<2; ++mt){
    #pragma unroll
    for (int ck=0; ck<2; ++ck){
      const size_t rowoff = (size_t)(t0 + mt*16 + lr)*64 + ck*32 + lk*8;
      short8 gv = *(const short8*)(gib + rowoff);
      #pragma unroll
      for (int j=0;j<8;++j) gif[mt][ck][j] = bf2f((ushort_t)gv[j]);
      gsf[mt][ck] = *(const short8*)(gsb + rowoff);
    }
  }
  const size_t liRow0 = (size_t)(t0 +      lr)*64 + d0;
  const size_t liRow1 = (size_t)(t0 + 16 + lr)*64 + d0;

  f32x4 acc[2][4];
  #pragma unroll
  for (int mt=0; mt<2; ++mt)
    #pragma unroll
    for (int et=0; et<4; ++et) acc[mt][et] = (f32x4){0,0,0,0};

  const char* wbase = (const char*)wgb + (size_t)d0*8192;
  short8 stg[4];
  {
    #pragma unroll
    for (int i=0;i<4;++i) stg[i] = *(const short8*)(wbase + (i*256 + t)*16);
    #pragma unroll
    for (int i=0;i<4;++i){
      int L = (i*256 + t)*16, R = L>>7, WB = L&127;
      *(short8*)(smem + R*128 + (WB ^ ((R&7)<<4))) = stg[i];
    }
  }
  __syncthreads();

  for (int g=0; g<8; ++g){
    const char* src = wbase + (size_t)(g+1)*16384;
    #pragma unroll
    for (int i=0;i<4;++i) stg[i] = *(const short8*)(src + (i*256 + t)*16);

    const char* buf = smem + (g&1)*16384;
    #pragma unroll
    for (int dd=0; dd<2; ++dd){
      const int d = g*2 + dd;
      short8 bfr[4][2];
      #pragma unroll
      for (int et=0; et<4; ++et){
        const int e = et*16 + lr;
        const int swz = (e&7)<<4;
        #pragma unroll
        for (int ck=0; ck<2; ++ck)
          bfr[et][ck] = *(const short8*)(buf + dd*8192 + e*128 + ((ck*64 + inrow) ^ swz));
      }
      const float lv0 = bf2f(lib[liRow0 + d]);
      const float lv1 = bf2f(lib[liRow1 + d]);
      short8 au0[2], au1[2];
      #pragma unroll
      for (int ck=0; ck<2; ++ck){
        au0[ck] = mulpack8(gif[0][ck], lv0);
        au1[ck] = mulpack8(gif[1][ck], lv1);
      }
      #pragma unroll
      for (int ck=0; ck<2; ++ck)
        #pragma unroll
        for (int et=0; et<4; ++et){
          acc[0][et] = __builtin_amdgcn_mfma_f32_16x16x32_bf16(au0[ck], bfr[et][ck], acc[0][et],0,0,0);
          acc[1][et] = __builtin_amdgcn_mfma_f32_16x16x32_bf16(au1[ck], bfr[et][ck], acc[1][et],0,0,0);
        }
    }

    char* dbuf = smem + ((g+1)&1)*16384;
    #pragma unroll
    for (int i=0;i<4;++i){
      int L = (i*256 + t)*16, R = L>>7, WB = L&127;
      *(short8*)(dbuf + R*128 + (WB ^ ((R&7)<<4))) = stg[i];
    }
    __syncthreads();
  }

  if (s == 3){
    const char* buf = smem;
    #pragma unroll
    for (int et=0; et<4; ++et){
      const int e = et*16 + lr;
      const int swz = (e&7)<<4;
      #pragma unroll
      for (int ck=0; ck<2; ++ck){
        short8 bfr = *(const short8*)(buf + e*128 + ((ck*64 + inrow) ^ swz));
        acc[0][et] = __builtin_amdgcn_mfma_f32_16x16x32_bf16(gsf[0][ck], bfr, acc[0][et],0,0,0);
        acc[1][et] = __builtin_amdgcn_mfma_f32_16x16x32_bf16(gsf[1][ck], bfr, acc[1][et],0,0,0);
      }
    }
  }

  float* dst = isap + (size_t)s*TOK*768;
  #pragma unroll
  for (int mt=0; mt<2; ++mt){
    #pragma unroll
    for (int et=0; et<4; ++et){
      #pragma unroll
      for (int r=0; r<4; ++r){
        int tok = t0 + mt*16 + lk*4 + r;
        int e = et*16 + lr;
        int bh = tok>>8, n = tok&255;
        int b = bh/12, h = bh - b*12;
        dst[((size_t)(b*256 + n))*768 + h*64 + e] = acc[mt][et][r];
      }
    }
  }
}

// ---------------------------------------------------------------------------
// K5: per-token LayerNorm(sa), LayerNorm(sum of isa partials), gated mix -> zb
__global__ __launch_bounds__(256) void k_lnmix(
    const float* __restrict__ saf, const float* __restrict__ isap,
    const float* __restrict__ lam, ushort_t* __restrict__ zb)
{
  int tok = blockIdx.x*4 + (threadIdx.x>>6);
  int l = threadIdx.x & 63;
  float g = 1.f/(1.f + __expf(-lam[0]));
  const float* sp = saf  + (size_t)tok*768;
  const float* p0 = isap + (size_t)tok*768;
  const float* p1 = p0 + (size_t)TOK*768;
  const float* p2 = p1 + (size_t)TOK*768;
  const float* p3 = p2 + (size_t)TOK*768;
  float sv[12], iv[12];
  float s1=0.f, s2=0.f, i1=0.f, i2=0.f;
  #pragma unroll
  for (int j=0;j<12;++j){
    int o = l + j*64;
    sv[j] = sp[o];  s1 += sv[j];  s2 += sv[j]*sv[j];
    iv[j] = (p0[o] + p1[o]) + (p2[o] + p3[o]);
    i1 += iv[j];  i2 += iv[j]*iv[j];
  }
  #pragma unroll
  for (int m=1; m<64; m<<=1){
    s1 += __shfl_xor(s1, m); s2 += __shfl_xor(s2, m);
    i1 += __shfl_xor(i1, m); i2 += __shfl_xor(i2, m);
  }
  float smean = s1*(1.f/768.f), svar = s2*(1.f/768.f) - smean*smean;
  float imean = i1*(1.f/768.f), ivar = i2*(1.f/768.f) - imean*imean;
  float sinv = 1.f/sqrtf(svar + 1e-5f);
  float iinv = 1.f/sqrtf(ivar + 1e-5f);
  #pragma unroll
  for (int j=0;j<12;++j){
    float z = g*(sv[j]-smean)*sinv + (1.f-g)*(iv[j]-imean)*iinv;
    zb[(size_t)tok*768 + l + j*64] = f2bf(z);
  }
}

// ---------------------------------------------------------------------------
// K6 v3: out = zb @ wpb^T + b_proj, double-buffered 2-phase (16 KB LDS)
__global__ __launch_bounds__(256) void k_outproj(
    const ushort_t* __restrict__ zb, const ushort_t* __restrict__ wpb,
    const float* __restrict__ bproj, float* __restrict__ out)
{
  __shared__ ushort_t As[2][64*32];
  __shared__ ushort_t Bs[2][64*32];
  const int n0 = blockIdx.x*64;
  const int m0 = blockIdx.y*64;
  const int t = threadIdx.x, w = t>>6, l = t&63;
  const int wr = w>>1, wc = w&1;
  const int lr = l&15, lk = l>>4;
  const int srow = w*16 + (l>>2);
  const int scol = ((l&3) ^ ((l>>3)&3)) << 3;
  const int sw = (lr>>1)&3;
  const int rdoff = (lk ^ sw)<<3;
  f32x4 acc00={0,0,0,0}, acc01={0,0,0,0}, acc10={0,0,0,0}, acc11={0,0,0,0};

  auto STAGE = [&](int bsel, int k0){
    glds16(zb  + (size_t)(m0+srow)*768 + k0 + scol, &As[bsel][w*512]);
    glds16(wpb + (size_t)(n0+srow)*768 + k0 + scol, &Bs[bsel][w*512]);
  };

  STAGE(0, 0);
  __syncthreads();

  for (int ts=0; ts<24; ++ts){
    const int cur = ts & 1;
    if (ts < 23) STAGE(cur^1, (ts+1)*32);
    const ushort_t* Ab = &As[cur][0];
    const ushort_t* Bb = &Bs[cur][0];
    short8 a0 = *(const short8*)(Ab + (wr*32 +      lr)*32 + rdoff);
    short8 a1 = *(const short8*)(Ab + (wr*32 + 16 + lr)*32 + rdoff);
    short8 b0 = *(const short8*)(Bb + (wc*32 +      lr)*32 + rdoff);
    short8 b1 = *(const short8*)(Bb + (wc*32 + 16 + lr)*32 + rdoff);
    acc00 = __builtin_amdgcn_mfma_f32_16x16x32_bf16(a0,b0,acc00,0,0,0);
    acc01 = __builtin_amdgcn_mfma_f32_16x16x32_bf16(a0,b1,acc01,0,0,0);
    acc10 = __builtin_amdgcn_mfma_f32_16x16x32_bf16(a1,b0,acc10,0,0,0);
    acc11 = __builtin_amdgcn_mfma_f32_16x16x32_bf16(a1,b1,acc11,0,0,0);
    __syncthreads();
  }

  #pragma unroll
  for (int fm=0; fm<2; ++fm){
    #pragma unroll
    for (int fn=0; fn<2; ++fn){
      f32x4 acc = (fm==0) ? ((fn==0)?acc00:acc01) : ((fn==0)?acc10:acc11);
      #pragma unroll
      for (int r=0; r<4; ++r){
        int grow = m0 + wr*32 + fm*16 + lk*4 + r;
        int gcol = n0 + wc*32 + fn*16 + lr;
        out[(size_t)grow*768 + gcol] = acc[r] + bproj[gcol];
      }
    }
  }
}

// ---------------------------------------------------------------------------
extern "C" void kernel_launch(void* const* d_in, const int* in_sizes, int n_in,
                              void* d_out, int out_size, void* d_ws, size_t ws_size,
                              hipStream_t stream)
{
  const float* x        = (const float*)d_in[0];
  const float* w_qkv    = (const float*)d_in[1];
  const float* b_qkv    = (const float*)d_in[2];
  const float* w_g      = (const float*)d_in[3];
  const float* w_bg     = (const float*)d_in[4];
  const float* w_local  = (const float*)d_in[5];
  const float* b_local  = (const float*)d_in[6];
  const float* w_globalp= (const float*)d_in[7];
  const float* b_globalp= (const float*)d_in[8];
  const float* lam      = (const float*)d_in[9];
  const float* w_proj   = (const float*)d_in[10];
  const float* b_proj   = (const float*)d_in[11];
  float* out = (float*)d_out;

  char* p = (char*)d_ws;
  auto alloc = [&](size_t bytes)->char*{
    char* r = p; p += (bytes + 255) & ~(size_t)255; return r;
  };
  ushort_t* wgb = (ushort_t*)alloc((size_t)72*4096*2);  // 65 used + prefetch pad
  ushort_t* qb  = (ushort_t*)alloc((size_t)THW*64*2);
  ushort_t* kb  = (ushort_t*)alloc((size_t)THW*64*2);
  ushort_t* vb  = (ushort_t*)alloc((size_t)THW*64*2);
  ushort_t* vT  = (ushort_t*)alloc((size_t)THW*64*2);
  ushort_t* giT = (ushort_t*)alloc((size_t)THW*64*2);
  ushort_t* gib = (ushort_t*)alloc((size_t)THW*64*2);
  ushort_t* lib = (ushort_t*)alloc((size_t)THW*64*2);
  ushort_t* gsb = (ushort_t*)alloc((size_t)THW*64*2);
  char*   Sreg  = alloc((size_t)BH*256*256*4);          // 25.17 MB region
  float*  rmaxb = (float*)  alloc((size_t)BH*256*4);
  float*  rsumb = (float*)  alloc((size_t)BH*256*4);
  float*  colpm = (float*)  alloc((size_t)BH*8*256*4);
  float*  colps = (float*)  alloc((size_t)BH*8*256*4);
  ushort_t* wpb = (ushort_t*)alloc((size_t)768*768*2);    // bf16 w_proj
  // Aliases over dead buffers:
  ushort_t* S16  = (ushort_t*)Sreg; // 12.6 MB bf16 S (dead after k_attnmm)
  float*    saf  = (float*)qb;      // over qb+kb (dead after k_logits)
  ushort_t* zb   = (ushort_t*)vb;   // over vb (dead after k_transpose)
  float*    isap = (float*)Sreg;    // 4 partials over S region
  ushort_t* xb   = (ushort_t*)Sreg;                   // dead after k_proj
  ushort_t* wb   = (ushort_t*)Sreg + (size_t)TOK*768; // dead after k_proj

  hipLaunchKernelGGL(k_pack, dim3(2626), dim3(256), 0, stream,
                     x, w_qkv, w_local, w_globalp, w_proj, w_g, w_bg,
                     xb, wb, wpb, wgb);
  hipLaunchKernelGGL(k_proj, dim3(60,16), dim3(256), 0, stream,
                     xb, wb, b_qkv, b_local, b_globalp,
                     qb, kb, vb, lib, gib);
  hipLaunchKernelGGL(k_transpose, dim3(96,2), dim3(256), 0, stream,
                     vb, gib, vT, giT);
  hipLaunchKernelGGL(k_logits, dim3(96,8), dim3(256), 0, stream,
                     qb, kb, S16, rmaxb, rsumb, colpm, colps);
  hipLaunchKernelGGL(k_attnmm, dim3(96,8), dim3(256), 0, stream,
                     S16, rmaxb, rsumb, colpm, colps, vT, giT, gsb, saf);
  hipLaunchKernelGGL(k_isa, dim3(192,4), dim3(256), 0, stream,
                     lib, gib, gsb, wgb, isap);
  hipLaunchKernelGGL(k_lnmix, dim3(512), dim3(256), 0, stream,
                     saf, isap, lam, zb);
  hipLaunchKernelGGL(k_outproj, dim3(12,32), dim3(256), 0, stream,
                     zb, wpb, b_proj, out);
}

// Round 16
// 122.520 us; speedup vs baseline: 1.0657x; 1.0657x over previous
//
#include <hip/hip_runtime.h>
#include <hip/hip_bf16.h>

// Problem constants
#define BH 96      // B*H
#define TOK 2048   // B*N
#define THW 24576  // B*H*N

typedef unsigned short ushort_t;
typedef __attribute__((ext_vector_type(8))) short short8;
typedef __attribute__((ext_vector_type(4))) float f32x4;

static __device__ __forceinline__ float bf2f(ushort_t u){
  union { unsigned int i; float f; } t; t.i = ((unsigned int)u)<<16; return t.f;
}
static __device__ __forceinline__ ushort_t f2bf(float f){
  union { float f; unsigned int i; } t; t.f = f;
  unsigned int u = t.i;
  return (ushort_t)((u + 0x7fffu + ((u>>16)&1u)) >> 16);
}
static __device__ __forceinline__ short8 pack8(f32x4 a, f32x4 b){
  short8 r;
  #pragma unroll
  for (int j=0;j<4;++j){ r[j]=(short)f2bf(a[j]); r[4+j]=(short)f2bf(b[j]); }
  return r;
}
static __device__ __forceinline__ float gelu_exact(float x){
  return 0.5f*x*(1.0f + erff(x*0.70710678118654752f));
}
// 8 f32 scaled by s -> bf16x8 (RNE via v_cvt_pk_bf16_f32)
static __device__ __forceinline__ short8 mulpack8(const float* f, float s){
  union { short8 s8; unsigned int u[4]; } r;
  #pragma unroll
  for (int j=0;j<4;++j){
    float2 p2; p2.x = f[2*j]*s; p2.y = f[2*j+1]*s;
    __hip_bfloat162 p = __float22bfloat162_rn(p2);
    r.u[j] = *(unsigned int*)&p;
  }
  return r.s8;
}
// async global->LDS, 16B per lane; LDS dest = uniform base + lane*16
static __device__ __forceinline__ void glds16(const ushort_t* g, ushort_t* l){
  __builtin_amdgcn_global_load_lds(
      (const __attribute__((address_space(1))) unsigned int*)g,
      (__attribute__((address_space(3))) unsigned int*)l, 16, 0, 0);
}

// ---------------------------------------------------------------------------
// K0: unified bf16 pack. Regions (elem offsets, all /8):
//  [0, 1572864)            x        -> xb
//  [1572864, 4521984)      wqkv/wl/wg -> wb
//  [4521984, 5111808)      w_proj   -> wpb
//  [5111808, 5378048)      w_g,w_bg -> wgb
__global__ __launch_bounds__(256) void k_pack(
    const float* __restrict__ x, const float* __restrict__ w_qkv,
    const float* __restrict__ w_local, const float* __restrict__ w_global,
    const float* __restrict__ w_proj, const float* __restrict__ w_g,
    const float* __restrict__ w_bg,
    ushort_t* __restrict__ xb, ushort_t* __restrict__ wb,
    ushort_t* __restrict__ wpb, ushort_t* __restrict__ wgb)
{
  size_t i = ((size_t)blockIdx.x*256 + threadIdx.x)*8;
  const float* src; ushort_t* dst; size_t off;
  if (i < 1572864){ src = x; dst = xb; off = i; }
  else if (i < 4521984){
    size_t j = i - 1572864; dst = wb; off = j;
    if (j < 1769472)      src = w_qkv;
    else if (j < 2359296) src = w_local - 1769472;
    else                  src = w_global - 2359296;
  }
  else if (i < 5111808){ off = i - 4521984; src = w_proj; dst = wpb; }
  else {
    size_t j = i - 5111808; dst = wgb; off = j;
    src = (j < 262144) ? w_g : (w_bg - 262144);
  }
  f32x4 a = *(const f32x4*)(src + off);
  f32x4 b = *(const f32x4*)(src + off + 4);
  *(short8*)(dst + off) = pack8(a, b);
}

// ---------------------------------------------------------------------------
// K1 v4 (best measured ~41-42us): 128x64 tile, BK=64, single-buffer 24KB,
// glds16 staging with chunk-XOR swizzle on both source col and ds_read.
__global__ __launch_bounds__(256) void k_proj(
    const ushort_t* __restrict__ xb, const ushort_t* __restrict__ wb,
    const float* __restrict__ b_qkv, const float* __restrict__ b_local,
    const float* __restrict__ b_global,
    ushort_t* __restrict__ qb, ushort_t* __restrict__ kb, ushort_t* __restrict__ vb,
    ushort_t* __restrict__ lib, ushort_t* __restrict__ gib)
{
  __shared__ ushort_t As[128*64];   // 16 KB
  __shared__ ushort_t Bs[64*64];    //  8 KB
  const int n0 = blockIdx.x*64;
  const int m0 = blockIdx.y*128;
  const int t = threadIdx.x, w = t>>6, l = t&63;
  const int wm = (w>>1)*64, wn = (w&1)*32;
  const int lr = l&15, lk = l>>4;               // lk 0..3
  const int sgrow = l>>3;                       // 0..7
  const int sgcol = ((l&7) ^ (l>>3))*8;         // inverse-swizzled elem col
  f32x4 acc[4][2];
  #pragma unroll
  for (int a=0;a<4;++a){ acc[a][0]=(f32x4){0,0,0,0}; acc[a][1]=(f32x4){0,0,0,0}; }

  for (int k0=0; k0<768; k0+=64){
    #pragma unroll
    for (int pp=0; pp<4; ++pp){
      int r0 = w*32 + pp*8;
      glds16(xb + (size_t)(m0+r0+sgrow)*768 + k0 + sgcol, As + r0*64);
    }
    #pragma unroll
    for (int pp=0; pp<2; ++pp){
      int r0 = w*16 + pp*8;
      glds16(wb + (size_t)(n0+r0+sgrow)*768 + k0 + sgcol, Bs + r0*64);
    }
    __syncthreads();
    short8 af[2][4], bf[2][2];
    #pragma unroll
    for (int kk=0; kk<2; ++kk){
      #pragma unroll
      for (int fm=0; fm<4; ++fm){
        int R = wm + fm*16 + lr;
        af[kk][fm] = *(const short8*)(As + R*64 + (((4*kk+lk) ^ (lr&7))*8));
      }
      #pragma unroll
      for (int fn=0; fn<2; ++fn){
        int R = wn + fn*16 + lr;
        bf[kk][fn] = *(const short8*)(Bs + R*64 + (((4*kk+lk) ^ (lr&7))*8));
      }
    }
    #pragma unroll
    for (int kk=0; kk<2; ++kk)
      #pragma unroll
      for (int fm=0; fm<4; ++fm)
        #pragma unroll
        for (int fn=0; fn<2; ++fn)
          acc[fm][fn] = __builtin_amdgcn_mfma_f32_16x16x32_bf16(af[kk][fm], bf[kk][fn], acc[fm][fn],0,0,0);
    __syncthreads();
  }

  #pragma unroll
  for (int fm=0; fm<4; ++fm){
    #pragma unroll
    for (int fn=0; fn<2; ++fn){
      #pragma unroll
      for (int r=0; r<4; ++r){
        int grow = m0 + wm + fm*16 + lk*4 + r;
        int colg = n0 + wn + fn*16 + lr;
        int b = grow>>8, n = grow&255;
        if (colg < 2304){
          float val = acc[fm][fn][r] + b_qkv[colg];
          int s = colg/768, rr = colg - s*768;
          int h = rr>>6, d = rr&63;
          size_t idx = ((size_t)(b*12+h)*256 + n)*64 + d;
          if (s==0)      qb[idx] = f2bf(val*0.125f);
          else if (s==1) kb[idx] = f2bf(val);
          else           vb[idx] = f2bf(val);
        } else if (colg < 3072){
          int cl = colg - 2304;
          float val = acc[fm][fn][r] + b_local[cl];
          int h = cl>>6, d = cl&63;
          lib[((size_t)(b*12+h)*256 + n)*64 + d] = f2bf(gelu_exact(val));
        } else {
          int cl = colg - 3072;
          float val = acc[fm][fn][r] + b_global[cl];
          int h = cl>>6, d = cl&63;
          gib[((size_t)(b*12+h)*256 + n)*64 + d] = f2bf(gelu_exact(val));
        }
      }
    }
  }
}

// ---------------------------------------------------------------------------
// K2: transpose [bh][m][e] -> [bh][e][m] for v and gi
__global__ __launch_bounds__(256) void k_transpose(
    const ushort_t* __restrict__ vb, const ushort_t* __restrict__ gib,
    ushort_t* __restrict__ vT, ushort_t* __restrict__ giT)
{
  int bh = blockIdx.x;
  const ushort_t* src = blockIdx.y ? gib : vb;
  ushort_t* dst       = blockIdx.y ? giT : vT;
  __shared__ ushort_t tile[256*72];
  int t = threadIdx.x;
  for (int i=t; i<2048; i+=256){
    int m = i>>3, e0 = (i&7)*8;
    *(short8*)(tile + m*72 + e0) =
      *(const short8*)(src + ((size_t)bh*256 + m)*64 + e0);
  }
  __syncthreads();
  for (int i=t; i<2048; i+=256){
    int e = i>>5, m0 = (i&31)*8;
    short8 v;
    #pragma unroll
    for (int j=0;j<8;++j) v[j] = (short)tile[(m0+j)*72 + e];
    *(short8*)(dst + ((size_t)bh*64 + e)*256 + m0) = v;
  }
}

// ---------------------------------------------------------------------------
// K3a v4: col-split x2 for occupancy. Grid (96,8): block = 32 rows.
__global__ __launch_bounds__(256) void k_logits(
    const ushort_t* __restrict__ qb, const ushort_t* __restrict__ kb,
    ushort_t* __restrict__ S, float* __restrict__ rmaxb, float* __restrict__ rsumb,
    float* __restrict__ colpm, float* __restrict__ colps)
{
  __shared__ float lpm[2][256], lps[2][256];   // [rg][ch*128+col]
  __shared__ float rpm[2][32], rps[2][32];     // [ch][row-in-block]
  int bh = blockIdx.x, n0 = blockIdx.y*32;
  int t = threadIdx.x, w = t>>6, l = t&63;
  int rg = w&1, ch = w>>1;
  int lr = l&15, lk = (l>>4)*8;
  int row = n0 + rg*16 + lr;
  const ushort_t* qp = qb + ((size_t)bh*256 + row)*64 + lk;
  short8 a0 = *(const short8*)(qp);
  short8 a1 = *(const short8*)(qp + 32);
  f32x4 acc[8];
  #pragma unroll
  for (int f=0; f<8; ++f) acc[f] = (f32x4){0,0,0,0};
  #pragma unroll
  for (int f=0; f<8; ++f){
    int col = ch*128 + f*16 + lr;
    const ushort_t* kp = kb + ((size_t)bh*256 + col)*64 + lk;
    short8 b0 = *(const short8*)(kp);
    short8 b1 = *(const short8*)(kp + 32);
    acc[f] = __builtin_amdgcn_mfma_f32_16x16x32_bf16(a0,b0,acc[f],0,0,0);
    acc[f] = __builtin_amdgcn_mfma_f32_16x16x32_bf16(a1,b1,acc[f],0,0,0);
  }
  #pragma unroll
  for (int r=0; r<4; ++r){
    int nl = rg*16 + (l>>4)*4 + r;            // row within block
    float mx = acc[0][r];
    #pragma unroll
    for (int f=1; f<8; ++f) mx = fmaxf(mx, acc[f][r]);
    mx = fmaxf(mx, __shfl_xor(mx, 1));
    mx = fmaxf(mx, __shfl_xor(mx, 2));
    mx = fmaxf(mx, __shfl_xor(mx, 4));
    mx = fmaxf(mx, __shfl_xor(mx, 8));
    float sm = 0.f;
    #pragma unroll
    for (int f=0; f<8; ++f) sm += __expf(acc[f][r] - mx);
    sm += __shfl_xor(sm, 1);
    sm += __shfl_xor(sm, 2);
    sm += __shfl_xor(sm, 4);
    sm += __shfl_xor(sm, 8);
    #pragma unroll
    for (int f=0; f<8; ++f)
      S[((size_t)bh*256 + n0 + nl)*256 + ch*128 + f*16 + lr] = f2bf(acc[f][r]);
    if (lr == 0){ rpm[ch][nl] = mx; rps[ch][nl] = sm; }
  }
  #pragma unroll
  for (int f=0; f<8; ++f){
    float pm = fmaxf(fmaxf(acc[f][0],acc[f][1]), fmaxf(acc[f][2],acc[f][3]));
    float ps = __expf(acc[f][0]-pm) + __expf(acc[f][1]-pm)
             + __expf(acc[f][2]-pm) + __expf(acc[f][3]-pm);
    #pragma unroll
    for (int m=16; m<64; m<<=1){
      float om = __shfl_xor(pm, m);
      float os = __shfl_xor(ps, m);
      float nm = fmaxf(pm, om);
      ps = ps*__expf(pm-nm) + os*__expf(om-nm);
      pm = nm;
    }
    if (l < 16){ lpm[rg][ch*128 + f*16 + lr] = pm; lps[rg][ch*128 + f*16 + lr] = ps; }
  }
  __syncthreads();
  if (t < 32){
    float M = rpm[0][t], Sm = rps[0][t];
    float om = rpm[1][t], os = rps[1][t];
    float nm = fmaxf(M, om);
    Sm = Sm*__expf(M-nm) + os*__expf(om-nm);
    rmaxb[bh*256 + n0 + t] = nm;
    rsumb[bh*256 + n0 + t] = Sm;
  }
  {
    float M = lpm[0][t], Sm = lps[0][t];
    float om = lpm[1][t], os = lps[1][t];
    float nm = fmaxf(M, om);
    Sm = Sm*__expf(M-nm) + os*__expf(om-nm);
    colpm[((size_t)bh*8 + blockIdx.y)*256 + t] = nm;
    colps[((size_t)bh*8 + blockIdx.y)*256 + t] = Sm;
  }
}

// ---------------------------------------------------------------------------
// K3c v4: kk-split x2 in-block + exp-factoring. Grid (96,8): block = 32 rows.
__global__ __launch_bounds__(256) void k_attnmm(
    const ushort_t* __restrict__ S,
    const float* __restrict__ rmaxb, const float* __restrict__ rsumb,
    const float* __restrict__ colpm, const float* __restrict__ colps,
    const ushort_t* __restrict__ vT, const ushort_t* __restrict__ giT,
    ushort_t* __restrict__ gsb, float* __restrict__ saf)
{
  __shared__ float ec_s[256];
  __shared__ float red[2][64][32];   // [rg][lane][8 x f32x4], XOR-swizzled
  int bh = blockIdx.x, n0 = blockIdx.y*32;
  int b = bh/12, h = bh - b*12;
  int t = threadIdx.x, w = t>>6, l = t&63;
  int rg = w&1, kh = w>>1;
  int lr = l&15;
  {
    const float* pm = colpm + (size_t)bh*2048;
    const float* ps = colps + (size_t)bh*2048;
    float M = pm[t], Ssum = ps[t];
    #pragma unroll
    for (int k=1; k<8; ++k){
      float om = pm[k*256+t], os = ps[k*256+t];
      float nm = fmaxf(M, om);
      Ssum = Ssum*__expf(M-nm) + os*__expf(om-nm);
      M = nm;
    }
    ec_s[t] = __expf(-M)/Ssum;
  }
  __syncthreads();
  int n = n0 + rg*16 + lr;   // A-fragment row
  float rmx = rmaxb[bh*256 + n];
  float er  = __expf(rmx);
  f32x4 asa[4], ags[4];
  #pragma unroll
  for (int fn=0; fn<4; ++fn){ asa[fn]=(f32x4){0,0,0,0}; ags[fn]=(f32x4){0,0,0,0}; }
  #pragma unroll
  for (int kq=0; kq<4; ++kq){
    int kk = kh*4 + kq;
    int mbase = kk*32 + (l>>4)*8;
    short8 sv = *(const short8*)(S + ((size_t)bh*256 + n)*256 + mbase);
    f32x4 ec_lo = *(const f32x4*)(ec_s + mbase);
    f32x4 ec_hi = *(const f32x4*)(ec_s + mbase + 4);
    short8 a_at, a_rat;
    #pragma unroll
    for (int j=0;j<4;++j){
      float e0 = __expf(bf2f((ushort_t)sv[j])   - rmx);
      float e1 = __expf(bf2f((ushort_t)sv[j+4]) - rmx);
      a_at[j]    = (short)f2bf(e0);
      a_at[j+4]  = (short)f2bf(e1);
      a_rat[j]   = (short)f2bf(e0 * er * ec_lo[j]);
      a_rat[j+4] = (short)f2bf(e1 * er * ec_hi[j]);
    }
    #pragma unroll
    for (int fn=0; fn<4; ++fn){
      int e = fn*16 + lr;
      short8 bv = *(const short8*)(vT  + ((size_t)bh*64 + e)*256 + mbase);
      short8 bg = *(const short8*)(giT + ((size_t)bh*64 + e)*256 + mbase);
      asa[fn] = __builtin_amdgcn_mfma_f32_16x16x32_bf16(a_at,  bv, asa[fn],0,0,0);
      ags[fn] = __builtin_amdgcn_mfma_f32_16x16x32_bf16(a_rat, bg, ags[fn],0,0,0);
    }
  }
  if (kh == 1){
    float* rp = &red[rg][l][0];
    #pragma unroll
    for (int fn=0; fn<4; ++fn){
      *(f32x4*)((char*)rp + (((2*fn)   ^ (l&7))*16)) = asa[fn];
      *(f32x4*)((char*)rp + (((2*fn+1) ^ (l&7))*16)) = ags[fn];
    }
  }
  __syncthreads();
  if (kh == 0){
    const float* rp = &red[rg][l][0];
    #pragma unroll
    for (int fn=0; fn<4; ++fn){
      f32x4 oa = *(const f32x4*)((const char*)rp + (((2*fn)   ^ (l&7))*16));
      f32x4 og = *(const f32x4*)((const char*)rp + (((2*fn+1) ^ (l&7))*16));
      asa[fn] += oa; ags[fn] += og;
    }
    #pragma unroll
    for (int r=0; r<4; ++r){
      int nr = n0 + rg*16 + (l>>4)*4 + r;
      float rinv = 1.0f / rsumb[bh*256 + nr];
      #pragma unroll
      for (int fn=0; fn<4; ++fn){
        int e = fn*16 + lr;
        saf[((size_t)(b*256 + nr))*768 + h*64 + e] = asa[fn][r] * rinv;
        gsb[((size_t)bh*256 + nr)*64 + e] = f2bf(ags[fn][r]);
      }
    }
  }
}

// ---------------------------------------------------------------------------
// K4 v3: K-split x4; partials -> isap[s]
__global__ __launch_bounds__(256) void k_isa(
    const ushort_t* __restrict__ lib, const ushort_t* __restrict__ gib,
    const ushort_t* __restrict__ gsb, const ushort_t* __restrict__ wgb,
    float* __restrict__ isap)
{
  __shared__ char smem[32768];   // 2 x 16KB granule buffers
  const int t = threadIdx.x, w = t>>6, l = t&63;
  const int lr = l&15, lk = l>>4;          // lk in 0..3
  const int t0 = blockIdx.x*128 + w*32;    // wave's first token
  const int s  = blockIdx.y;               // K-split 0..3
  const int d0 = s*16;
  const int inrow = lk*16;

  float  gif[2][2][8];
  short8 gsf[2][2];
  #pragma unroll
  for (int mt=0; mt<2; ++mt){
    #pragma unroll
    for (int ck=0; ck<2; ++ck){
      const size_t rowoff = (size_t)(t0 + mt*16 + lr)*64 + ck*32 + lk*8;
      short8 gv = *(const short8*)(gib + rowoff);
      #pragma unroll
      for (int j=0;j<8;++j) gif[mt][ck][j] = bf2f((ushort_t)gv[j]);
      gsf[mt][ck] = *(const short8*)(gsb + rowoff);
    }
  }
  const size_t liRow0 = (size_t)(t0 +      lr)*64 + d0;
  const size_t liRow1 = (size_t)(t0 + 16 + lr)*64 + d0;

  f32x4 acc[2][4];
  #pragma unroll
  for (int mt=0; mt<2; ++mt)
    #pragma unroll
    for (int et=0; et<4; ++et) acc[mt][et] = (f32x4){0,0,0,0};

  const char* wbase = (const char*)wgb + (size_t)d0*8192;
  short8 stg[4];
  {
    #pragma unroll
    for (int i=0;i<4;++i) stg[i] = *(const short8*)(wbase + (i*256 + t)*16);
    #pragma unroll
    for (int i=0;i<4;++i){
      int L = (i*256 + t)*16, R = L>>7, WB = L&127;
      *(short8*)(smem + R*128 + (WB ^ ((R&7)<<4))) = stg[i];
    }
  }
  __syncthreads();

  for (int g=0; g<8; ++g){
    const char* src = wbase + (size_t)(g+1)*16384;
    #pragma unroll
    for (int i=0;i<4;++i) stg[i] = *(const short8*)(src + (i*256 + t)*16);

    const char* buf = smem + (g&1)*16384;
    #pragma unroll
    for (int dd=0; dd<2; ++dd){
      const int d = g*2 + dd;
      short8 bfr[4][2];
      #pragma unroll
      for (int et=0; et<4; ++et){
        const int e = et*16 + lr;
        const int swz = (e&7)<<4;
        #pragma unroll
        for (int ck=0; ck<2; ++ck)
          bfr[et][ck] = *(const short8*)(buf + dd*8192 + e*128 + ((ck*64 + inrow) ^ swz));
      }
      const float lv0 = bf2f(lib[liRow0 + d]);
      const float lv1 = bf2f(lib[liRow1 + d]);
      short8 au0[2], au1[2];
      #pragma unroll
      for (int ck=0; ck<2; ++ck){
        au0[ck] = mulpack8(gif[0][ck], lv0);
        au1[ck] = mulpack8(gif[1][ck], lv1);
      }
      #pragma unroll
      for (int ck=0; ck<2; ++ck)
        #pragma unroll
        for (int et=0; et<4; ++et){
          acc[0][et] = __builtin_amdgcn_mfma_f32_16x16x32_bf16(au0[ck], bfr[et][ck], acc[0][et],0,0,0);
          acc[1][et] = __builtin_amdgcn_mfma_f32_16x16x32_bf16(au1[ck], bfr[et][ck], acc[1][et],0,0,0);
        }
    }

    char* dbuf = smem + ((g+1)&1)*16384;
    #pragma unroll
    for (int i=0;i<4;++i){
      int L = (i*256 + t)*16, R = L>>7, WB = L&127;
      *(short8*)(dbuf + R*128 + (WB ^ ((R&7)<<4))) = stg[i];
    }
    __syncthreads();
  }

  if (s == 3){
    const char* buf = smem;
    #pragma unroll
    for (int et=0; et<4; ++et){
      const int e = et*16 + lr;
      const int swz = (e&7)<<4;
      #pragma unroll
      for (int ck=0; ck<2; ++ck){
        short8 bfr = *(const short8*)(buf + e*128 + ((ck*64 + inrow) ^ swz));
        acc[0][et] = __builtin_amdgcn_mfma_f32_16x16x32_bf16(gsf[0][ck], bfr, acc[0][et],0,0,0);
        acc[1][et] = __builtin_amdgcn_mfma_f32_16x16x32_bf16(gsf[1][ck], bfr, acc[1][et],0,0,0);
      }
    }
  }

  float* dst = isap + (size_t)s*TOK*768;
  #pragma unroll
  for (int mt=0; mt<2; ++mt){
    #pragma unroll
    for (int et=0; et<4; ++et){
      #pragma unroll
      for (int r=0; r<4; ++r){
        int tok = t0 + mt*16 + lk*4 + r;
        int e = et*16 + lr;
        int bh = tok>>8, n = tok&255;
        int b = bh/12, h = bh - b*12;
        dst[((size_t)(b*256 + n))*768 + h*64 + e] = acc[mt][et][r];
      }
    }
  }
}

// ---------------------------------------------------------------------------
// K5: per-token LayerNorm(sa), LayerNorm(sum of isa partials), gated mix -> zb
__global__ __launch_bounds__(256) void k_lnmix(
    const float* __restrict__ saf, const float* __restrict__ isap,
    const float* __restrict__ lam, ushort_t* __restrict__ zb)
{
  int tok = blockIdx.x*4 + (threadIdx.x>>6);
  int l = threadIdx.x & 63;
  float g = 1.f/(1.f + __expf(-lam[0]));
  const float* sp = saf  + (size_t)tok*768;
  const float* p0 = isap + (size_t)tok*768;
  const float* p1 = p0 + (size_t)TOK*768;
  const float* p2 = p1 + (size_t)TOK*768;
  const float* p3 = p2 + (size_t)TOK*768;
  float sv[12], iv[12];
  float s1=0.f, s2=0.f, i1=0.f, i2=0.f;
  #pragma unroll
  for (int j=0;j<12;++j){
    int o = l + j*64;
    sv[j] = sp[o];  s1 += sv[j];  s2 += sv[j]*sv[j];
    iv[j] = (p0[o] + p1[o]) + (p2[o] + p3[o]);
    i1 += iv[j];  i2 += iv[j]*iv[j];
  }
  #pragma unroll
  for (int m=1; m<64; m<<=1){
    s1 += __shfl_xor(s1, m); s2 += __shfl_xor(s2, m);
    i1 += __shfl_xor(i1, m); i2 += __shfl_xor(i2, m);
  }
  float smean = s1*(1.f/768.f), svar = s2*(1.f/768.f) - smean*smean;
  float imean = i1*(1.f/768.f), ivar = i2*(1.f/768.f) - imean*imean;
  float sinv = 1.f/sqrtf(svar + 1e-5f);
  float iinv = 1.f/sqrtf(ivar + 1e-5f);
  #pragma unroll
  for (int j=0;j<12;++j){
    float z = g*(sv[j]-smean)*sinv + (1.f-g)*(iv[j]-imean)*iinv;
    zb[(size_t)tok*768 + l + j*64] = f2bf(z);
  }
}

// ---------------------------------------------------------------------------
// K6 v2: out = zb @ wpb^T + b_proj (all-bf16, glds16+swizzle, 64^2 tile)
__global__ __launch_bounds__(256) void k_outproj(
    const ushort_t* __restrict__ zb, const ushort_t* __restrict__ wpb,
    const float* __restrict__ bproj, float* __restrict__ out)
{
  __shared__ ushort_t As[64*32];
  __shared__ ushort_t Bs[64*32];
  const int n0 = blockIdx.x*64;
  const int m0 = blockIdx.y*64;
  const int t = threadIdx.x, w = t>>6, l = t&63;
  const int wr = w>>1, wc = w&1;
  const int lr = l&15, lk = l>>4;
  const int srow = w*16 + (l>>2);
  const int scol = ((l&3) ^ ((l>>3)&3)) << 3;
  const int sw = (lr>>1)&3;
  const int rdoff = (lk ^ sw)<<3;
  f32x4 acc00={0,0,0,0}, acc01={0,0,0,0}, acc10={0,0,0,0}, acc11={0,0,0,0};

  for (int k0=0; k0<768; k0+=32){
    glds16(zb  + (size_t)(m0+srow)*768 + k0 + scol, As + w*512);
    glds16(wpb + (size_t)(n0+srow)*768 + k0 + scol, Bs + w*512);
    __syncthreads();
    short8 a0 = *(const short8*)(As + (wr*32 +      lr)*32 + rdoff);
    short8 a1 = *(const short8*)(As + (wr*32 + 16 + lr)*32 + rdoff);
    short8 b0 = *(const short8*)(Bs + (wc*32 +      lr)*32 + rdoff);
    short8 b1 = *(const short8*)(Bs + (wc*32 + 16 + lr)*32 + rdoff);
    acc00 = __builtin_amdgcn_mfma_f32_16x16x32_bf16(a0,b0,acc00,0,0,0);
    acc01 = __builtin_amdgcn_mfma_f32_16x16x32_bf16(a0,b1,acc01,0,0,0);
    acc10 = __builtin_amdgcn_mfma_f32_16x16x32_bf16(a1,b0,acc10,0,0,0);
    acc11 = __builtin_amdgcn_mfma_f32_16x16x32_bf16(a1,b1,acc11,0,0,0);
    __syncthreads();
  }

  #pragma unroll
  for (int fm=0; fm<2; ++fm){
    #pragma unroll
    for (int fn=0; fn<2; ++fn){
      f32x4 acc = (fm==0) ? ((fn==0)?acc00:acc01) : ((fn==0)?acc10:acc11);
      #pragma unroll
      for (int r=0; r<4; ++r){
        int grow = m0 + wr*32 + fm*16 + lk*4 + r;
        int gcol = n0 + wc*32 + fn*16 + lr;
        out[(size_t)grow*768 + gcol] = acc[r] + bproj[gcol];
      }
    }
  }
}

// ---------------------------------------------------------------------------
extern "C" void kernel_launch(void* const* d_in, const int* in_sizes, int n_in,
                              void* d_out, int out_size, void* d_ws, size_t ws_size,
                              hipStream_t stream)
{
  const float* x        = (const float*)d_in[0];
  const float* w_qkv    = (const float*)d_in[1];
  const float* b_qkv    = (const float*)d_in[2];
  const float* w_g      = (const float*)d_in[3];
  const float* w_bg     = (const float*)d_in[4];
  const float* w_local  = (const float*)d_in[5];
  const float* b_local  = (const float*)d_in[6];
  const float* w_globalp= (const float*)d_in[7];
  const float* b_globalp= (const float*)d_in[8];
  const float* lam      = (const float*)d_in[9];
  const float* w_proj   = (const float*)d_in[10];
  const float* b_proj   = (const float*)d_in[11];
  float* out = (float*)d_out;

  char* p = (char*)d_ws;
  auto alloc = [&](size_t bytes)->char*{
    char* r = p; p += (bytes + 255) & ~(size_t)255; return r;
  };
  ushort_t* wgb = (ushort_t*)alloc((size_t)72*4096*2);  // 65 used + prefetch pad
  ushort_t* qb  = (ushort_t*)alloc((size_t)THW*64*2);
  ushort_t* kb  = (ushort_t*)alloc((size_t)THW*64*2);
  ushort_t* vb  = (ushort_t*)alloc((size_t)THW*64*2);
  ushort_t* vT  = (ushort_t*)alloc((size_t)THW*64*2);
  ushort_t* giT = (ushort_t*)alloc((size_t)THW*64*2);
  ushort_t* gib = (ushort_t*)alloc((size_t)THW*64*2);
  ushort_t* lib = (ushort_t*)alloc((size_t)THW*64*2);
  ushort_t* gsb = (ushort_t*)alloc((size_t)THW*64*2);
  char*   Sreg  = alloc((size_t)BH*256*256*4);          // 25.17 MB region
  float*  rmaxb = (float*)  alloc((size_t)BH*256*4);
  float*  rsumb = (float*)  alloc((size_t)BH*256*4);
  float*  colpm = (float*)  alloc((size_t)BH*8*256*4);
  float*  colps = (float*)  alloc((size_t)BH*8*256*4);
  ushort_t* wpb = (ushort_t*)alloc((size_t)768*768*2);    // bf16 w_proj
  // Aliases over dead buffers:
  ushort_t* S16  = (ushort_t*)Sreg; // 12.6 MB bf16 S (dead after k_attnmm)
  float*    saf  = (float*)qb;      // over qb+kb (dead after k_logits)
  ushort_t* zb   = (ushort_t*)vb;   // over vb (dead after k_transpose)
  float*    isap = (float*)Sreg;    // 4 partials over S region
  ushort_t* xb   = (ushort_t*)Sreg;                   // dead after k_proj
  ushort_t* wb   = (ushort_t*)Sreg + (size_t)TOK*768; // dead after k_proj

  hipLaunchKernelGGL(k_pack, dim3(2626), dim3(256), 0, stream,
                     x, w_qkv, w_local, w_globalp, w_proj, w_g, w_bg,
                     xb, wb, wpb, wgb);
  hipLaunchKernelGGL(k_proj, dim3(60,16), dim3(256), 0, stream,
                     xb, wb, b_qkv, b_local, b_globalp,
                     qb, kb, vb, lib, gib);
  hipLaunchKernelGGL(k_transpose, dim3(96,2), dim3(256), 0, stream,
                     vb, gib, vT, giT);
  hipLaunchKernelGGL(k_logits, dim3(96,8), dim3(256), 0, stream,
                     qb, kb, S16, rmaxb, rsumb, colpm, colps);
  hipLaunchKernelGGL(k_attnmm, dim3(96,8), dim3(256), 0, stream,
                     S16, rmaxb, rsumb, colpm, colps, vT, giT, gsb, saf);
  hipLaunchKernelGGL(k_isa, dim3(192,4), dim3(256), 0, stream,
                     lib, gib, gsb, wgb, isap);
  hipLaunchKernelGGL(k_lnmix, dim3(512), dim3(256), 0, stream,
                     saf, isap, lam, zb);
  hipLaunchKernelGGL(k_outproj, dim3(12,32), dim3(256), 0, stream,
                     zb, wpb, b_proj, out);
}

// Round 17
// 111.333 us; speedup vs baseline: 1.1728x; 1.1005x over previous
//
#include <hip/hip_runtime.h>
#include <hip/hip_bf16.h>

// Problem constants
#define BH 96      // B*H
#define TOK 2048   // B*N
#define THW 24576  // B*H*N

typedef unsigned short ushort_t;
typedef __attribute__((ext_vector_type(8))) short short8;
typedef __attribute__((ext_vector_type(4))) short short4_t;
typedef __attribute__((ext_vector_type(4))) float f32x4;

static __device__ __forceinline__ float bf2f(ushort_t u){
  union { unsigned int i; float f; } t; t.i = ((unsigned int)u)<<16; return t.f;
}
static __device__ __forceinline__ ushort_t f2bf(float f){
  union { float f; unsigned int i; } t; t.f = f;
  unsigned int u = t.i;
  return (ushort_t)((u + 0x7fffu + ((u>>16)&1u)) >> 16);
}
static __device__ __forceinline__ short8 pack8(f32x4 a, f32x4 b){
  short8 r;
  #pragma unroll
  for (int j=0;j<4;++j){ r[j]=(short)f2bf(a[j]); r[4+j]=(short)f2bf(b[j]); }
  return r;
}
static __device__ __forceinline__ float gelu_exact(float x){
  return 0.5f*x*(1.0f + erff(x*0.70710678118654752f));
}
// 8 f32 scaled by s -> bf16x8 (RNE via v_cvt_pk_bf16_f32)
static __device__ __forceinline__ short8 mulpack8(const float* f, float s){
  union { short8 s8; unsigned int u[4]; } r;
  #pragma unroll
  for (int j=0;j<4;++j){
    float2 p2; p2.x = f[2*j]*s; p2.y = f[2*j+1]*s;
    __hip_bfloat162 p = __float22bfloat162_rn(p2);
    r.u[j] = *(unsigned int*)&p;
  }
  return r.s8;
}
// async global->LDS, 16B per lane; LDS dest = uniform base + lane*16
static __device__ __forceinline__ void glds16(const ushort_t* g, ushort_t* l){
  __builtin_amdgcn_global_load_lds(
      (const __attribute__((address_space(1))) unsigned int*)g,
      (__attribute__((address_space(3))) unsigned int*)l, 16, 0, 0);
}

// ---------------------------------------------------------------------------
// K0: unified bf16 pack. Regions (elem offsets, all /8):
//  [0, 1572864)            x        -> xb
//  [1572864, 4521984)      wqkv/wl/wg -> wb
//  [4521984, 5111808)      w_proj   -> wpb
//  [5111808, 5378048)      w_g,w_bg -> wgb
__global__ __launch_bounds__(256) void k_pack(
    const float* __restrict__ x, const float* __restrict__ w_qkv,
    const float* __restrict__ w_local, const float* __restrict__ w_global,
    const float* __restrict__ w_proj, const float* __restrict__ w_g,
    const float* __restrict__ w_bg,
    ushort_t* __restrict__ xb, ushort_t* __restrict__ wb,
    ushort_t* __restrict__ wpb, ushort_t* __restrict__ wgb)
{
  size_t i = ((size_t)blockIdx.x*256 + threadIdx.x)*8;
  const float* src; ushort_t* dst; size_t off;
  if (i < 1572864){ src = x; dst = xb; off = i; }
  else if (i < 4521984){
    size_t j = i - 1572864; dst = wb; off = j;
    if (j < 1769472)      src = w_qkv;
    else if (j < 2359296) src = w_local - 1769472;
    else                  src = w_global - 2359296;
  }
  else if (i < 5111808){ off = i - 4521984; src = w_proj; dst = wpb; }
  else {
    size_t j = i - 5111808; dst = wgb; off = j;
    src = (j < 262144) ? w_g : (w_bg - 262144);
  }
  f32x4 a = *(const f32x4*)(src + off);
  f32x4 b = *(const f32x4*)(src + off + 4);
  *(short8*)(dst + off) = pack8(a, b);
}

// ---------------------------------------------------------------------------
// K1 v5: 128x64 tile, BK=64, single-buffer 24KB (best measured structure).
// Epilogue now writes vT and giT DIRECTLY (transposed, packed 8B stores);
// v row-major copy eliminated; k_transpose kernel removed.
__global__ __launch_bounds__(256) void k_proj(
    const ushort_t* __restrict__ xb, const ushort_t* __restrict__ wb,
    const float* __restrict__ b_qkv, const float* __restrict__ b_local,
    const float* __restrict__ b_global,
    ushort_t* __restrict__ qb, ushort_t* __restrict__ kb,
    ushort_t* __restrict__ vT, ushort_t* __restrict__ lib,
    ushort_t* __restrict__ gib, ushort_t* __restrict__ giT)
{
  __shared__ ushort_t As[128*64];   // 16 KB
  __shared__ ushort_t Bs[64*64];    //  8 KB
  const int n0 = blockIdx.x*64;
  const int m0 = blockIdx.y*128;
  const int t = threadIdx.x, w = t>>6, l = t&63;
  const int wm = (w>>1)*64, wn = (w&1)*32;
  const int lr = l&15, lk = l>>4;               // lk 0..3
  const int sgrow = l>>3;                       // 0..7
  const int sgcol = ((l&7) ^ (l>>3))*8;         // inverse-swizzled elem col
  f32x4 acc[4][2];
  #pragma unroll
  for (int a=0;a<4;++a){ acc[a][0]=(f32x4){0,0,0,0}; acc[a][1]=(f32x4){0,0,0,0}; }

  for (int k0=0; k0<768; k0+=64){
    #pragma unroll
    for (int pp=0; pp<4; ++pp){
      int r0 = w*32 + pp*8;
      glds16(xb + (size_t)(m0+r0+sgrow)*768 + k0 + sgcol, As + r0*64);
    }
    #pragma unroll
    for (int pp=0; pp<2; ++pp){
      int r0 = w*16 + pp*8;
      glds16(wb + (size_t)(n0+r0+sgrow)*768 + k0 + sgcol, Bs + r0*64);
    }
    __syncthreads();
    short8 af[2][4], bf[2][2];
    #pragma unroll
    for (int kk=0; kk<2; ++kk){
      #pragma unroll
      for (int fm=0; fm<4; ++fm){
        int R = wm + fm*16 + lr;
        af[kk][fm] = *(const short8*)(As + R*64 + (((4*kk+lk) ^ (lr&7))*8));
      }
      #pragma unroll
      for (int fn=0; fn<2; ++fn){
        int R = wn + fn*16 + lr;
        bf[kk][fn] = *(const short8*)(Bs + R*64 + (((4*kk+lk) ^ (lr&7))*8));
      }
    }
    #pragma unroll
    for (int kk=0; kk<2; ++kk)
      #pragma unroll
      for (int fm=0; fm<4; ++fm)
        #pragma unroll
        for (int fn=0; fn<2; ++fn)
          acc[fm][fn] = __builtin_amdgcn_mfma_f32_16x16x32_bf16(af[kk][fm], bf[kk][fn], acc[fm][fn],0,0,0);
    __syncthreads();
  }

  #pragma unroll
  for (int fm=0; fm<4; ++fm){
    #pragma unroll
    for (int fn=0; fn<2; ++fn){
      const int grow0 = m0 + wm + fm*16 + lk*4;   // first of 4 consecutive rows
      const int colg  = n0 + wn + fn*16 + lr;
      const int b = grow0>>8, nloc = grow0&255;   // 4 rows stay in-batch (128|m0)
      if (colg < 1536){
        // q (scaled) / k : row-major scalar stores
        #pragma unroll
        for (int r=0; r<4; ++r){
          float val = acc[fm][fn][r] + b_qkv[colg];
          int s = colg>>9 >= 1 ? 1 : 0;  // placeholder, recomputed below
          (void)s;
          int h = (colg - ((colg<768)?0:768))>>6, d = colg&63;
          size_t idx = ((size_t)(b*12+h)*256 + nloc + r)*64 + d;
          if (colg < 768) qb[idx] = f2bf(val*0.125f);
          else            kb[idx] = f2bf(val);
        }
      } else if (colg < 2304){
        // v: transposed packed store [bh][d][n]
        int rr = colg - 1536;
        int h = rr>>6, d = rr&63;
        short4_t pk;
        #pragma unroll
        for (int r=0; r<4; ++r)
          pk[r] = (short)f2bf(acc[fm][fn][r] + b_qkv[colg]);
        *(short4_t*)(vT + ((size_t)(b*12+h)*64 + d)*256 + nloc) = pk;
      } else if (colg < 3072){
        // li: row-major scalar stores
        int cl = colg - 2304;
        int h = cl>>6, d = cl&63;
        #pragma unroll
        for (int r=0; r<4; ++r){
          float val = acc[fm][fn][r] + b_local[cl];
          lib[((size_t)(b*12+h)*256 + nloc + r)*64 + d] = f2bf(gelu_exact(val));
        }
      } else {
        // gi: row-major scalars + transposed packed copy
        int cl = colg - 3072;
        int h = cl>>6, d = cl&63;
        short4_t pk;
        #pragma unroll
        for (int r=0; r<4; ++r){
          float gv = gelu_exact(acc[fm][fn][r] + b_global[cl]);
          ushort_t gb = f2bf(gv);
          gib[((size_t)(b*12+h)*256 + nloc + r)*64 + d] = gb;
          pk[r] = (short)gb;
        }
        *(short4_t*)(giT + ((size_t)(b*12+h)*64 + d)*256 + nloc) = pk;
      }
    }
  }
}

// ---------------------------------------------------------------------------
// K3a v4: col-split x2 for occupancy. Grid (96,8): block = 32 rows.
__global__ __launch_bounds__(256) void k_logits(
    const ushort_t* __restrict__ qb, const ushort_t* __restrict__ kb,
    ushort_t* __restrict__ S, float* __restrict__ rmaxb, float* __restrict__ rsumb,
    float* __restrict__ colpm, float* __restrict__ colps)
{
  __shared__ float lpm[2][256], lps[2][256];   // [rg][ch*128+col]
  __shared__ float rpm[2][32], rps[2][32];     // [ch][row-in-block]
  int bh = blockIdx.x, n0 = blockIdx.y*32;
  int t = threadIdx.x, w = t>>6, l = t&63;
  int rg = w&1, ch = w>>1;
  int lr = l&15, lk = (l>>4)*8;
  int row = n0 + rg*16 + lr;
  const ushort_t* qp = qb + ((size_t)bh*256 + row)*64 + lk;
  short8 a0 = *(const short8*)(qp);
  short8 a1 = *(const short8*)(qp + 32);
  f32x4 acc[8];
  #pragma unroll
  for (int f=0; f<8; ++f) acc[f] = (f32x4){0,0,0,0};
  #pragma unroll
  for (int f=0; f<8; ++f){
    int col = ch*128 + f*16 + lr;
    const ushort_t* kp = kb + ((size_t)bh*256 + col)*64 + lk;
    short8 b0 = *(const short8*)(kp);
    short8 b1 = *(const short8*)(kp + 32);
    acc[f] = __builtin_amdgcn_mfma_f32_16x16x32_bf16(a0,b0,acc[f],0,0,0);
    acc[f] = __builtin_amdgcn_mfma_f32_16x16x32_bf16(a1,b1,acc[f],0,0,0);
  }
  #pragma unroll
  for (int r=0; r<4; ++r){
    int nl = rg*16 + (l>>4)*4 + r;            // row within block
    float mx = acc[0][r];
    #pragma unroll
    for (int f=1; f<8; ++f) mx = fmaxf(mx, acc[f][r]);
    mx = fmaxf(mx, __shfl_xor(mx, 1));
    mx = fmaxf(mx, __shfl_xor(mx, 2));
    mx = fmaxf(mx, __shfl_xor(mx, 4));
    mx = fmaxf(mx, __shfl_xor(mx, 8));
    float sm = 0.f;
    #pragma unroll
    for (int f=0; f<8; ++f) sm += __expf(acc[f][r] - mx);
    sm += __shfl_xor(sm, 1);
    sm += __shfl_xor(sm, 2);
    sm += __shfl_xor(sm, 4);
    sm += __shfl_xor(sm, 8);
    #pragma unroll
    for (int f=0; f<8; ++f)
      S[((size_t)bh*256 + n0 + nl)*256 + ch*128 + f*16 + lr] = f2bf(acc[f][r]);
    if (lr == 0){ rpm[ch][nl] = mx; rps[ch][nl] = sm; }
  }
  #pragma unroll
  for (int f=0; f<8; ++f){
    float pm = fmaxf(fmaxf(acc[f][0],acc[f][1]), fmaxf(acc[f][2],acc[f][3]));
    float ps = __expf(acc[f][0]-pm) + __expf(acc[f][1]-pm)
             + __expf(acc[f][2]-pm) + __expf(acc[f][3]-pm);
    #pragma unroll
    for (int m=16; m<64; m<<=1){
      float om = __shfl_xor(pm, m);
      float os = __shfl_xor(ps, m);
      float nm = fmaxf(pm, om);
      ps = ps*__expf(pm-nm) + os*__expf(om-nm);
      pm = nm;
    }
    if (l < 16){ lpm[rg][ch*128 + f*16 + lr] = pm; lps[rg][ch*128 + f*16 + lr] = ps; }
  }
  __syncthreads();
  if (t < 32){
    float M = rpm[0][t], Sm = rps[0][t];
    float om = rpm[1][t], os = rps[1][t];
    float nm = fmaxf(M, om);
    Sm = Sm*__expf(M-nm) + os*__expf(om-nm);
    rmaxb[bh*256 + n0 + t] = nm;
    rsumb[bh*256 + n0 + t] = Sm;
  }
  {
    float M = lpm[0][t], Sm = lps[0][t];
    float om = lpm[1][t], os = lps[1][t];
    float nm = fmaxf(M, om);
    Sm = Sm*__expf(M-nm) + os*__expf(om-nm);
    colpm[((size_t)bh*8 + blockIdx.y)*256 + t] = nm;
    colps[((size_t)bh*8 + blockIdx.y)*256 + t] = Sm;
  }
}

// ---------------------------------------------------------------------------
// K3c v4: kk-split x2 in-block + exp-factoring. Grid (96,8): block = 32 rows.
__global__ __launch_bounds__(256) void k_attnmm(
    const ushort_t* __restrict__ S,
    const float* __restrict__ rmaxb, const float* __restrict__ rsumb,
    const float* __restrict__ colpm, const float* __restrict__ colps,
    const ushort_t* __restrict__ vT, const ushort_t* __restrict__ giT,
    ushort_t* __restrict__ gsb, float* __restrict__ saf)
{
  __shared__ float ec_s[256];
  __shared__ float red[2][64][32];   // [rg][lane][8 x f32x4], XOR-swizzled
  int bh = blockIdx.x, n0 = blockIdx.y*32;
  int b = bh/12, h = bh - b*12;
  int t = threadIdx.x, w = t>>6, l = t&63;
  int rg = w&1, kh = w>>1;
  int lr = l&15;
  {
    const float* pm = colpm + (size_t)bh*2048;
    const float* ps = colps + (size_t)bh*2048;
    float M = pm[t], Ssum = ps[t];
    #pragma unroll
    for (int k=1; k<8; ++k){
      float om = pm[k*256+t], os = ps[k*256+t];
      float nm = fmaxf(M, om);
      Ssum = Ssum*__expf(M-nm) + os*__expf(om-nm);
      M = nm;
    }
    ec_s[t] = __expf(-M)/Ssum;
  }
  __syncthreads();
  int n = n0 + rg*16 + lr;   // A-fragment row
  float rmx = rmaxb[bh*256 + n];
  float er  = __expf(rmx);
  f32x4 asa[4], ags[4];
  #pragma unroll
  for (int fn=0; fn<4; ++fn){ asa[fn]=(f32x4){0,0,0,0}; ags[fn]=(f32x4){0,0,0,0}; }
  #pragma unroll
  for (int kq=0; kq<4; ++kq){
    int kk = kh*4 + kq;
    int mbase = kk*32 + (l>>4)*8;
    short8 sv = *(const short8*)(S + ((size_t)bh*256 + n)*256 + mbase);
    f32x4 ec_lo = *(const f32x4*)(ec_s + mbase);
    f32x4 ec_hi = *(const f32x4*)(ec_s + mbase + 4);
    short8 a_at, a_rat;
    #pragma unroll
    for (int j=0;j<4;++j){
      float e0 = __expf(bf2f((ushort_t)sv[j])   - rmx);
      float e1 = __expf(bf2f((ushort_t)sv[j+4]) - rmx);
      a_at[j]    = (short)f2bf(e0);
      a_at[j+4]  = (short)f2bf(e1);
      a_rat[j]   = (short)f2bf(e0 * er * ec_lo[j]);
      a_rat[j+4] = (short)f2bf(e1 * er * ec_hi[j]);
    }
    #pragma unroll
    for (int fn=0; fn<4; ++fn){
      int e = fn*16 + lr;
      short8 bv = *(const short8*)(vT  + ((size_t)bh*64 + e)*256 + mbase);
      short8 bg = *(const short8*)(giT + ((size_t)bh*64 + e)*256 + mbase);
      asa[fn] = __builtin_amdgcn_mfma_f32_16x16x32_bf16(a_at,  bv, asa[fn],0,0,0);
      ags[fn] = __builtin_amdgcn_mfma_f32_16x16x32_bf16(a_rat, bg, ags[fn],0,0,0);
    }
  }
  if (kh == 1){
    float* rp = &red[rg][l][0];
    #pragma unroll
    for (int fn=0; fn<4; ++fn){
      *(f32x4*)((char*)rp + (((2*fn)   ^ (l&7))*16)) = asa[fn];
      *(f32x4*)((char*)rp + (((2*fn+1) ^ (l&7))*16)) = ags[fn];
    }
  }
  __syncthreads();
  if (kh == 0){
    const float* rp = &red[rg][l][0];
    #pragma unroll
    for (int fn=0; fn<4; ++fn){
      f32x4 oa = *(const f32x4*)((const char*)rp + (((2*fn)   ^ (l&7))*16));
      f32x4 og = *(const f32x4*)((const char*)rp + (((2*fn+1) ^ (l&7))*16));
      asa[fn] += oa; ags[fn] += og;
    }
    #pragma unroll
    for (int r=0; r<4; ++r){
      int nr = n0 + rg*16 + (l>>4)*4 + r;
      float rinv = 1.0f / rsumb[bh*256 + nr];
      #pragma unroll
      for (int fn=0; fn<4; ++fn){
        int e = fn*16 + lr;
        saf[((size_t)(b*256 + nr))*768 + h*64 + e] = asa[fn][r] * rinv;
        gsb[((size_t)bh*256 + nr)*64 + e] = f2bf(ags[fn][r]);
      }
    }
  }
}

// ---------------------------------------------------------------------------
// K4 v3: K-split x4; partials -> isap[s]
__global__ __launch_bounds__(256) void k_isa(
    const ushort_t* __restrict__ lib, const ushort_t* __restrict__ gib,
    const ushort_t* __restrict__ gsb, const ushort_t* __restrict__ wgb,
    float* __restrict__ isap)
{
  __shared__ char smem[32768];   // 2 x 16KB granule buffers
  const int t = threadIdx.x, w = t>>6, l = t&63;
  const int lr = l&15, lk = l>>4;          // lk in 0..3
  const int t0 = blockIdx.x*128 + w*32;    // wave's first token
  const int s  = blockIdx.y;               // K-split 0..3
  const int d0 = s*16;
  const int inrow = lk*16;

  float  gif[2][2][8];
  short8 gsf[2][2];
  #pragma unroll
  for (int mt=0; mt<2; ++mt){
    #pragma unroll
    for (int ck=0; ck<2; ++ck){
      const size_t rowoff = (size_t)(t0 + mt*16 + lr)*64 + ck*32 + lk*8;
      short8 gv = *(const short8*)(gib + rowoff);
      #pragma unroll
      for (int j=0;j<8;++j) gif[mt][ck][j] = bf2f((ushort_t)gv[j]);
      gsf[mt][ck] = *(const short8*)(gsb + rowoff);
    }
  }
  const size_t liRow0 = (size_t)(t0 +      lr)*64 + d0;
  const size_t liRow1 = (size_t)(t0 + 16 + lr)*64 + d0;

  f32x4 acc[2][4];
  #pragma unroll
  for (int mt=0; mt<2; ++mt)
    #pragma unroll
    for (int et=0; et<4; ++et) acc[mt][et] = (f32x4){0,0,0,0};

  const char* wbase = (const char*)wgb + (size_t)d0*8192;
  short8 stg[4];
  {
    #pragma unroll
    for (int i=0;i<4;++i) stg[i] = *(const short8*)(wbase + (i*256 + t)*16);
    #pragma unroll
    for (int i=0;i<4;++i){
      int L = (i*256 + t)*16, R = L>>7, WB = L&127;
      *(short8*)(smem + R*128 + (WB ^ ((R&7)<<4))) = stg[i];
    }
  }
  __syncthreads();

  for (int g=0; g<8; ++g){
    const char* src = wbase + (size_t)(g+1)*16384;
    #pragma unroll
    for (int i=0;i<4;++i) stg[i] = *(const short8*)(src + (i*256 + t)*16);

    const char* buf = smem + (g&1)*16384;
    #pragma unroll
    for (int dd=0; dd<2; ++dd){
      const int d = g*2 + dd;
      short8 bfr[4][2];
      #pragma unroll
      for (int et=0; et<4; ++et){
        const int e = et*16 + lr;
        const int swz = (e&7)<<4;
        #pragma unroll
        for (int ck=0; ck<2; ++ck)
          bfr[et][ck] = *(const short8*)(buf + dd*8192 + e*128 + ((ck*64 + inrow) ^ swz));
      }
      const float lv0 = bf2f(lib[liRow0 + d]);
      const float lv1 = bf2f(lib[liRow1 + d]);
      short8 au0[2], au1[2];
      #pragma unroll
      for (int ck=0; ck<2; ++ck){
        au0[ck] = mulpack8(gif[0][ck], lv0);
        au1[ck] = mulpack8(gif[1][ck], lv1);
      }
      #pragma unroll
      for (int ck=0; ck<2; ++ck)
        #pragma unroll
        for (int et=0; et<4; ++et){
          acc[0][et] = __builtin_amdgcn_mfma_f32_16x16x32_bf16(au0[ck], bfr[et][ck], acc[0][et],0,0,0);
          acc[1][et] = __builtin_amdgcn_mfma_f32_16x16x32_bf16(au1[ck], bfr[et][ck], acc[1][et],0,0,0);
        }
    }

    char* dbuf = smem + ((g+1)&1)*16384;
    #pragma unroll
    for (int i=0;i<4;++i){
      int L = (i*256 + t)*16, R = L>>7, WB = L&127;
      *(short8*)(dbuf + R*128 + (WB ^ ((R&7)<<4))) = stg[i];
    }
    __syncthreads();
  }

  if (s == 3){
    const char* buf = smem;
    #pragma unroll
    for (int et=0; et<4; ++et){
      const int e = et*16 + lr;
      const int swz = (e&7)<<4;
      #pragma unroll
      for (int ck=0; ck<2; ++ck){
        short8 bfr = *(const short8*)(buf + e*128 + ((ck*64 + inrow) ^ swz));
        acc[0][et] = __builtin_amdgcn_mfma_f32_16x16x32_bf16(gsf[0][ck], bfr, acc[0][et],0,0,0);
        acc[1][et] = __builtin_amdgcn_mfma_f32_16x16x32_bf16(gsf[1][ck], bfr, acc[1][et],0,0,0);
      }
    }
  }

  float* dst = isap + (size_t)s*TOK*768;
  #pragma unroll
  for (int mt=0; mt<2; ++mt){
    #pragma unroll
    for (int et=0; et<4; ++et){
      #pragma unroll
      for (int r=0; r<4; ++r){
        int tok = t0 + mt*16 + lk*4 + r;
        int e = et*16 + lr;
        int bh = tok>>8, n = tok&255;
        int b = bh/12, h = bh - b*12;
        dst[((size_t)(b*256 + n))*768 + h*64 + e] = acc[mt][et][r];
      }
    }
  }
}

// ---------------------------------------------------------------------------
// K5: per-token LayerNorm(sa), LayerNorm(sum of isa partials), gated mix -> zb
__global__ __launch_bounds__(256) void k_lnmix(
    const float* __restrict__ saf, const float* __restrict__ isap,
    const float* __restrict__ lam, ushort_t* __restrict__ zb)
{
  int tok = blockIdx.x*4 + (threadIdx.x>>6);
  int l = threadIdx.x & 63;
  float g = 1.f/(1.f + __expf(-lam[0]));
  const float* sp = saf  + (size_t)tok*768;
  const float* p0 = isap + (size_t)tok*768;
  const float* p1 = p0 + (size_t)TOK*768;
  const float* p2 = p1 + (size_t)TOK*768;
  const float* p3 = p2 + (size_t)TOK*768;
  float sv[12], iv[12];
  float s1=0.f, s2=0.f, i1=0.f, i2=0.f;
  #pragma unroll
  for (int j=0;j<12;++j){
    int o = l + j*64;
    sv[j] = sp[o];  s1 += sv[j];  s2 += sv[j]*sv[j];
    iv[j] = (p0[o] + p1[o]) + (p2[o] + p3[o]);
    i1 += iv[j];  i2 += iv[j]*iv[j];
  }
  #pragma unroll
  for (int m=1; m<64; m<<=1){
    s1 += __shfl_xor(s1, m); s2 += __shfl_xor(s2, m);
    i1 += __shfl_xor(i1, m); i2 += __shfl_xor(i2, m);
  }
  float smean = s1*(1.f/768.f), svar = s2*(1.f/768.f) - smean*smean;
  float imean = i1*(1.f/768.f), ivar = i2*(1.f/768.f) - imean*imean;
  float sinv = 1.f/sqrtf(svar + 1e-5f);
  float iinv = 1.f/sqrtf(ivar + 1e-5f);
  #pragma unroll
  for (int j=0;j<12;++j){
    float z = g*(sv[j]-smean)*sinv + (1.f-g)*(iv[j]-imean)*iinv;
    zb[(size_t)tok*768 + l + j*64] = f2bf(z);
  }
}

// ---------------------------------------------------------------------------
// K6 v2: out = zb @ wpb^T + b_proj (all-bf16, glds16+swizzle, 64^2 tile)
__global__ __launch_bounds__(256) void k_outproj(
    const ushort_t* __restrict__ zb, const ushort_t* __restrict__ wpb,
    const float* __restrict__ bproj, float* __restrict__ out)
{
  __shared__ ushort_t As[64*32];
  __shared__ ushort_t Bs[64*32];
  const int n0 = blockIdx.x*64;
  const int m0 = blockIdx.y*64;
  const int t = threadIdx.x, w = t>>6, l = t&63;
  const int wr = w>>1, wc = w&1;
  const int lr = l&15, lk = l>>4;
  const int srow = w*16 + (l>>2);
  const int scol = ((l&3) ^ ((l>>3)&3)) << 3;
  const int sw = (lr>>1)&3;
  const int rdoff = (lk ^ sw)<<3;
  f32x4 acc00={0,0,0,0}, acc01={0,0,0,0}, acc10={0,0,0,0}, acc11={0,0,0,0};

  for (int k0=0; k0<768; k0+=32){
    glds16(zb  + (size_t)(m0+srow)*768 + k0 + scol, As + w*512);
    glds16(wpb + (size_t)(n0+srow)*768 + k0 + scol, Bs + w*512);
    __syncthreads();
    short8 a0 = *(const short8*)(As + (wr*32 +      lr)*32 + rdoff);
    short8 a1 = *(const short8*)(As + (wr*32 + 16 + lr)*32 + rdoff);
    short8 b0 = *(const short8*)(Bs + (wc*32 +      lr)*32 + rdoff);
    short8 b1 = *(const short8*)(Bs + (wc*32 + 16 + lr)*32 + rdoff);
    acc00 = __builtin_amdgcn_mfma_f32_16x16x32_bf16(a0,b0,acc00,0,0,0);
    acc01 = __builtin_amdgcn_mfma_f32_16x16x32_bf16(a0,b1,acc01,0,0,0);
    acc10 = __builtin_amdgcn_mfma_f32_16x16x32_bf16(a1,b0,acc10,0,0,0);
    acc11 = __builtin_amdgcn_mfma_f32_16x16x32_bf16(a1,b1,acc11,0,0,0);
    __syncthreads();
  }

  #pragma unroll
  for (int fm=0; fm<2; ++fm){
    #pragma unroll
    for (int fn=0; fn<2; ++fn){
      f32x4 acc = (fm==0) ? ((fn==0)?acc00:acc01) : ((fn==0)?acc10:acc11);
      #pragma unroll
      for (int r=0; r<4; ++r){
        int grow = m0 + wr*32 + fm*16 + lk*4 + r;
        int gcol = n0 + wc*32 + fn*16 + lr;
        out[(size_t)grow*768 + gcol] = acc[r] + bproj[gcol];
      }
    }
  }
}

// ---------------------------------------------------------------------------
extern "C" void kernel_launch(void* const* d_in, const int* in_sizes, int n_in,
                              void* d_out, int out_size, void* d_ws, size_t ws_size,
                              hipStream_t stream)
{
  const float* x        = (const float*)d_in[0];
  const float* w_qkv    = (const float*)d_in[1];
  const float* b_qkv    = (const float*)d_in[2];
  const float* w_g      = (const float*)d_in[3];
  const float* w_bg     = (const float*)d_in[4];
  const float* w_local  = (const float*)d_in[5];
  const float* b_local  = (const float*)d_in[6];
  const float* w_globalp= (const float*)d_in[7];
  const float* b_globalp= (const float*)d_in[8];
  const float* lam      = (const float*)d_in[9];
  const float* w_proj   = (const float*)d_in[10];
  const float* b_proj   = (const float*)d_in[11];
  float* out = (float*)d_out;

  char* p = (char*)d_ws;
  auto alloc = [&](size_t bytes)->char*{
    char* r = p; p += (bytes + 255) & ~(size_t)255; return r;
  };
  ushort_t* wgb = (ushort_t*)alloc((size_t)72*4096*2);  // 65 used + prefetch pad
  ushort_t* qb  = (ushort_t*)alloc((size_t)THW*64*2);
  ushort_t* kb  = (ushort_t*)alloc((size_t)THW*64*2);
  ushort_t* vT  = (ushort_t*)alloc((size_t)THW*64*2);
  ushort_t* giT = (ushort_t*)alloc((size_t)THW*64*2);
  ushort_t* gib = (ushort_t*)alloc((size_t)THW*64*2);
  ushort_t* lib = (ushort_t*)alloc((size_t)THW*64*2);
  ushort_t* gsb = (ushort_t*)alloc((size_t)THW*64*2);
  char*   Sreg  = alloc((size_t)BH*256*256*4);          // 25.17 MB region
  float*  rmaxb = (float*)  alloc((size_t)BH*256*4);
  float*  rsumb = (float*)  alloc((size_t)BH*256*4);
  float*  colpm = (float*)  alloc((size_t)BH*8*256*4);
  float*  colps = (float*)  alloc((size_t)BH*8*256*4);
  ushort_t* wpb = (ushort_t*)alloc((size_t)768*768*2);    // bf16 w_proj
  // Aliases over dead buffers:
  ushort_t* S16  = (ushort_t*)Sreg; // 12.6 MB bf16 S (dead after k_attnmm)
  float*    saf  = (float*)qb;      // over qb+kb (dead after k_logits)
  ushort_t* zb   = (ushort_t*)gsb;  // over gsb (dead after k_isa)
  float*    isap = (float*)Sreg;    // 4 partials over S region
  ushort_t* xb   = (ushort_t*)Sreg;                   // dead after k_proj
  ushort_t* wb   = (ushort_t*)Sreg + (size_t)TOK*768; // dead after k_proj

  hipLaunchKernelGGL(k_pack, dim3(2626), dim3(256), 0, stream,
                     x, w_qkv, w_local, w_globalp, w_proj, w_g, w_bg,
                     xb, wb, wpb, wgb);
  hipLaunchKernelGGL(k_proj, dim3(60,16), dim3(256), 0, stream,
                     xb, wb, b_qkv, b_local, b_globalp,
                     qb, kb, vT, lib, gib, giT);
  hipLaunchKernelGGL(k_logits, dim3(96,8), dim3(256), 0, stream,
                     qb, kb, S16, rmaxb, rsumb, colpm, colps);
  hipLaunchKernelGGL(k_attnmm, dim3(96,8), dim3(256), 0, stream,
                     S16, rmaxb, rsumb, colpm, colps, vT, giT, gsb, saf);
  hipLaunchKernelGGL(k_isa, dim3(192,4), dim3(256), 0, stream,
                     lib, gib, gsb, wgb, isap);
  hipLaunchKernelGGL(k_lnmix, dim3(512), dim3(256), 0, stream,
                     saf, isap, lam, zb);
  hipLaunchKernelGGL(k_outproj, dim3(12,32), dim3(256), 0, stream,
                     zb, wpb, b_proj, out);
}

// Round 18
// 110.010 us; speedup vs baseline: 1.1869x; 1.0120x over previous
//
#include <hip/hip_runtime.h>
#include <hip/hip_bf16.h>

// Problem constants
#define BH 96      // B*H
#define TOK 2048   // B*N
#define THW 24576  // B*H*N

typedef unsigned short ushort_t;
typedef __attribute__((ext_vector_type(8))) short short8;
typedef __attribute__((ext_vector_type(4))) short short4_t;
typedef __attribute__((ext_vector_type(4))) float f32x4;

static __device__ __forceinline__ float bf2f(ushort_t u){
  union { unsigned int i; float f; } t; t.i = ((unsigned int)u)<<16; return t.f;
}
static __device__ __forceinline__ ushort_t f2bf(float f){
  union { float f; unsigned int i; } t; t.f = f;
  unsigned int u = t.i;
  return (ushort_t)((u + 0x7fffu + ((u>>16)&1u)) >> 16);
}
static __device__ __forceinline__ short8 pack8(f32x4 a, f32x4 b){
  short8 r;
  #pragma unroll
  for (int j=0;j<4;++j){ r[j]=(short)f2bf(a[j]); r[4+j]=(short)f2bf(b[j]); }
  return r;
}
static __device__ __forceinline__ float gelu_exact(float x){
  return 0.5f*x*(1.0f + erff(x*0.70710678118654752f));
}
// 8 f32 scaled by s -> bf16x8 (RNE via v_cvt_pk_bf16_f32)
static __device__ __forceinline__ short8 mulpack8(const float* f, float s){
  union { short8 s8; unsigned int u[4]; } r;
  #pragma unroll
  for (int j=0;j<4;++j){
    float2 p2; p2.x = f[2*j]*s; p2.y = f[2*j+1]*s;
    __hip_bfloat162 p = __float22bfloat162_rn(p2);
    r.u[j] = *(unsigned int*)&p;
  }
  return r.s8;
}
// async global->LDS, 16B per lane; LDS dest = uniform base + lane*16
static __device__ __forceinline__ void glds16(const ushort_t* g, ushort_t* l){
  __builtin_amdgcn_global_load_lds(
      (const __attribute__((address_space(1))) unsigned int*)g,
      (__attribute__((address_space(3))) unsigned int*)l, 16, 0, 0);
}

// ---------------------------------------------------------------------------
// K0: unified bf16 pack.
__global__ __launch_bounds__(256) void k_pack(
    const float* __restrict__ x, const float* __restrict__ w_qkv,
    const float* __restrict__ w_local, const float* __restrict__ w_global,
    const float* __restrict__ w_proj, const float* __restrict__ w_g,
    const float* __restrict__ w_bg,
    ushort_t* __restrict__ xb, ushort_t* __restrict__ wb,
    ushort_t* __restrict__ wpb, ushort_t* __restrict__ wgb)
{
  size_t i = ((size_t)blockIdx.x*256 + threadIdx.x)*8;
  const float* src; ushort_t* dst; size_t off;
  if (i < 1572864){ src = x; dst = xb; off = i; }
  else if (i < 4521984){
    size_t j = i - 1572864; dst = wb; off = j;
    if (j < 1769472)      src = w_qkv;
    else if (j < 2359296) src = w_local - 1769472;
    else                  src = w_global - 2359296;
  }
  else if (i < 5111808){ off = i - 4521984; src = w_proj; dst = wpb; }
  else {
    size_t j = i - 5111808; dst = wgb; off = j;
    src = (j < 262144) ? w_g : (w_bg - 262144);
  }
  f32x4 a = *(const f32x4*)(src + off);
  f32x4 b = *(const f32x4*)(src + off + 4);
  *(short8*)(dst + off) = pack8(a, b);
}

// ---------------------------------------------------------------------------
// K1 v5: 128x64 tile, BK=64, single-buffer 24KB; epilogue writes vT/giT
// directly (transposed packed 8B stores).
__global__ __launch_bounds__(256) void k_proj(
    const ushort_t* __restrict__ xb, const ushort_t* __restrict__ wb,
    const float* __restrict__ b_qkv, const float* __restrict__ b_local,
    const float* __restrict__ b_global,
    ushort_t* __restrict__ qb, ushort_t* __restrict__ kb,
    ushort_t* __restrict__ vT, ushort_t* __restrict__ lib,
    ushort_t* __restrict__ gib, ushort_t* __restrict__ giT)
{
  __shared__ ushort_t As[128*64];   // 16 KB
  __shared__ ushort_t Bs[64*64];    //  8 KB
  const int n0 = blockIdx.x*64;
  const int m0 = blockIdx.y*128;
  const int t = threadIdx.x, w = t>>6, l = t&63;
  const int wm = (w>>1)*64, wn = (w&1)*32;
  const int lr = l&15, lk = l>>4;               // lk 0..3
  const int sgrow = l>>3;                       // 0..7
  const int sgcol = ((l&7) ^ (l>>3))*8;         // inverse-swizzled elem col
  f32x4 acc[4][2];
  #pragma unroll
  for (int a=0;a<4;++a){ acc[a][0]=(f32x4){0,0,0,0}; acc[a][1]=(f32x4){0,0,0,0}; }

  for (int k0=0; k0<768; k0+=64){
    #pragma unroll
    for (int pp=0; pp<4; ++pp){
      int r0 = w*32 + pp*8;
      glds16(xb + (size_t)(m0+r0+sgrow)*768 + k0 + sgcol, As + r0*64);
    }
    #pragma unroll
    for (int pp=0; pp<2; ++pp){
      int r0 = w*16 + pp*8;
      glds16(wb + (size_t)(n0+r0+sgrow)*768 + k0 + sgcol, Bs + r0*64);
    }
    __syncthreads();
    short8 af[2][4], bf[2][2];
    #pragma unroll
    for (int kk=0; kk<2; ++kk){
      #pragma unroll
      for (int fm=0; fm<4; ++fm){
        int R = wm + fm*16 + lr;
        af[kk][fm] = *(const short8*)(As + R*64 + (((4*kk+lk) ^ (lr&7))*8));
      }
      #pragma unroll
      for (int fn=0; fn<2; ++fn){
        int R = wn + fn*16 + lr;
        bf[kk][fn] = *(const short8*)(Bs + R*64 + (((4*kk+lk) ^ (lr&7))*8));
      }
    }
    #pragma unroll
    for (int kk=0; kk<2; ++kk)
      #pragma unroll
      for (int fm=0; fm<4; ++fm)
        #pragma unroll
        for (int fn=0; fn<2; ++fn)
          acc[fm][fn] = __builtin_amdgcn_mfma_f32_16x16x32_bf16(af[kk][fm], bf[kk][fn], acc[fm][fn],0,0,0);
    __syncthreads();
  }

  #pragma unroll
  for (int fm=0; fm<4; ++fm){
    #pragma unroll
    for (int fn=0; fn<2; ++fn){
      const int grow0 = m0 + wm + fm*16 + lk*4;   // first of 4 consecutive rows
      const int colg  = n0 + wn + fn*16 + lr;
      const int b = grow0>>8, nloc = grow0&255;   // 4 rows stay in-batch (128|m0)
      if (colg < 1536){
        #pragma unroll
        for (int r=0; r<4; ++r){
          float val = acc[fm][fn][r] + b_qkv[colg];
          int h = (colg - ((colg<768)?0:768))>>6, d = colg&63;
          size_t idx = ((size_t)(b*12+h)*256 + nloc + r)*64 + d;
          if (colg < 768) qb[idx] = f2bf(val*0.125f);
          else            kb[idx] = f2bf(val);
        }
      } else if (colg < 2304){
        int rr = colg - 1536;
        int h = rr>>6, d = rr&63;
        short4_t pk;
        #pragma unroll
        for (int r=0; r<4; ++r)
          pk[r] = (short)f2bf(acc[fm][fn][r] + b_qkv[colg]);
        *(short4_t*)(vT + ((size_t)(b*12+h)*64 + d)*256 + nloc) = pk;
      } else if (colg < 3072){
        int cl = colg - 2304;
        int h = cl>>6, d = cl&63;
        #pragma unroll
        for (int r=0; r<4; ++r){
          float val = acc[fm][fn][r] + b_local[cl];
          lib[((size_t)(b*12+h)*256 + nloc + r)*64 + d] = f2bf(gelu_exact(val));
        }
      } else {
        int cl = colg - 3072;
        int h = cl>>6, d = cl&63;
        short4_t pk;
        #pragma unroll
        for (int r=0; r<4; ++r){
          float gv = gelu_exact(acc[fm][fn][r] + b_global[cl]);
          ushort_t gb = f2bf(gv);
          gib[((size_t)(b*12+h)*256 + nloc + r)*64 + d] = gb;
          pk[r] = (short)gb;
        }
        *(short4_t*)(giT + ((size_t)(b*12+h)*64 + d)*256 + nloc) = pk;
      }
    }
  }
}

// ---------------------------------------------------------------------------
// K3a v5: col-split x2; stores P = exp(s - rmax_full) in bf16 (not raw s).
// Partial exps kept in regs; rescaled by exp(mx_part - rmax_full) post-combine.
__global__ __launch_bounds__(256) void k_logits(
    const ushort_t* __restrict__ qb, const ushort_t* __restrict__ kb,
    ushort_t* __restrict__ P, float* __restrict__ rmaxb, float* __restrict__ rsumb,
    float* __restrict__ colpm, float* __restrict__ colps)
{
  __shared__ float lpm[2][256], lps[2][256];   // [rg][ch*128+col]
  __shared__ float rpm[2][32], rps[2][32];     // [ch][row-in-block]
  __shared__ float rmax_s[32];
  int bh = blockIdx.x, n0 = blockIdx.y*32;
  int t = threadIdx.x, w = t>>6, l = t&63;
  int rg = w&1, ch = w>>1;
  int lr = l&15, lk = (l>>4)*8;
  int row = n0 + rg*16 + lr;
  const ushort_t* qp = qb + ((size_t)bh*256 + row)*64 + lk;
  short8 a0 = *(const short8*)(qp);
  short8 a1 = *(const short8*)(qp + 32);
  f32x4 acc[8];
  #pragma unroll
  for (int f=0; f<8; ++f) acc[f] = (f32x4){0,0,0,0};
  #pragma unroll
  for (int f=0; f<8; ++f){
    int col = ch*128 + f*16 + lr;
    const ushort_t* kp = kb + ((size_t)bh*256 + col)*64 + lk;
    short8 b0 = *(const short8*)(kp);
    short8 b1 = *(const short8*)(kp + 32);
    acc[f] = __builtin_amdgcn_mfma_f32_16x16x32_bf16(a0,b0,acc[f],0,0,0);
    acc[f] = __builtin_amdgcn_mfma_f32_16x16x32_bf16(a1,b1,acc[f],0,0,0);
  }
  // row partial stats; keep e = exp(acc - mx_part) in registers
  f32x4 e[8];
  float mxp[4];
  #pragma unroll
  for (int r=0; r<4; ++r){
    int nl = rg*16 + (l>>4)*4 + r;            // row within block
    float mx = acc[0][r];
    #pragma unroll
    for (int f=1; f<8; ++f) mx = fmaxf(mx, acc[f][r]);
    mx = fmaxf(mx, __shfl_xor(mx, 1));
    mx = fmaxf(mx, __shfl_xor(mx, 2));
    mx = fmaxf(mx, __shfl_xor(mx, 4));
    mx = fmaxf(mx, __shfl_xor(mx, 8));
    mxp[r] = mx;
    float sm = 0.f;
    #pragma unroll
    for (int f=0; f<8; ++f){ e[f][r] = __expf(acc[f][r] - mx); sm += e[f][r]; }
    sm += __shfl_xor(sm, 1);
    sm += __shfl_xor(sm, 2);
    sm += __shfl_xor(sm, 4);
    sm += __shfl_xor(sm, 8);
    if (lr == 0){ rpm[ch][nl] = mx; rps[ch][nl] = sm; }
  }
  // col partials (raw s)
  #pragma unroll
  for (int f=0; f<8; ++f){
    float pm = fmaxf(fmaxf(acc[f][0],acc[f][1]), fmaxf(acc[f][2],acc[f][3]));
    float ps = __expf(acc[f][0]-pm) + __expf(acc[f][1]-pm)
             + __expf(acc[f][2]-pm) + __expf(acc[f][3]-pm);
    #pragma unroll
    for (int m=16; m<64; m<<=1){
      float om = __shfl_xor(pm, m);
      float os = __shfl_xor(ps, m);
      float nm = fmaxf(pm, om);
      ps = ps*__expf(pm-nm) + os*__expf(om-nm);
      pm = nm;
    }
    if (l < 16){ lpm[rg][ch*128 + f*16 + lr] = pm; lps[rg][ch*128 + f*16 + lr] = ps; }
  }
  __syncthreads();
  if (t < 32){
    float M = rpm[0][t], Sm = rps[0][t];
    float om = rpm[1][t], os = rps[1][t];
    float nm = fmaxf(M, om);
    Sm = Sm*__expf(M-nm) + os*__expf(om-nm);
    rmaxb[bh*256 + n0 + t] = nm;
    rsumb[bh*256 + n0 + t] = Sm;
    rmax_s[t] = nm;
  }
  {
    float M = lpm[0][t], Sm = lps[0][t];
    float om = lpm[1][t], os = lps[1][t];
    float nm = fmaxf(M, om);
    Sm = Sm*__expf(M-nm) + os*__expf(om-nm);
    colpm[((size_t)bh*8 + blockIdx.y)*256 + t] = nm;
    colps[((size_t)bh*8 + blockIdx.y)*256 + t] = Sm;
  }
  __syncthreads();
  // P store: rescale partial exps by exp(mx_part - rmax_full)
  #pragma unroll
  for (int r=0; r<4; ++r){
    int nl = rg*16 + (l>>4)*4 + r;
    float sc = __expf(mxp[r] - rmax_s[nl]);
    #pragma unroll
    for (int f=0; f<8; ++f)
      P[((size_t)bh*256 + n0 + nl)*256 + ch*128 + f*16 + lr] = f2bf(e[f][r]*sc);
  }
}

// ---------------------------------------------------------------------------
// K3c v5: A-fragments from stored P — a_at = P verbatim (no VALU);
// a_rat = P * er * ec. kk-split x2 + LDS combine unchanged.
__global__ __launch_bounds__(256) void k_attnmm(
    const ushort_t* __restrict__ P,
    const float* __restrict__ rmaxb, const float* __restrict__ rsumb,
    const float* __restrict__ colpm, const float* __restrict__ colps,
    const ushort_t* __restrict__ vT, const ushort_t* __restrict__ giT,
    ushort_t* __restrict__ gsb, float* __restrict__ saf)
{
  __shared__ float ec_s[256];
  __shared__ float red[2][64][32];   // [rg][lane][8 x f32x4], XOR-swizzled
  int bh = blockIdx.x, n0 = blockIdx.y*32;
  int b = bh/12, h = bh - b*12;
  int t = threadIdx.x, w = t>>6, l = t&63;
  int rg = w&1, kh = w>>1;
  int lr = l&15;
  {
    const float* pm = colpm + (size_t)bh*2048;
    const float* ps = colps + (size_t)bh*2048;
    float M = pm[t], Ssum = ps[t];
    #pragma unroll
    for (int k=1; k<8; ++k){
      float om = pm[k*256+t], os = ps[k*256+t];
      float nm = fmaxf(M, om);
      Ssum = Ssum*__expf(M-nm) + os*__expf(om-nm);
      M = nm;
    }
    ec_s[t] = __expf(-M)/Ssum;
  }
  __syncthreads();
  int n = n0 + rg*16 + lr;   // A-fragment row
  float er = __expf(rmaxb[bh*256 + n]);
  f32x4 asa[4], ags[4];
  #pragma unroll
  for (int fn=0; fn<4; ++fn){ asa[fn]=(f32x4){0,0,0,0}; ags[fn]=(f32x4){0,0,0,0}; }
  #pragma unroll
  for (int kq=0; kq<4; ++kq){
    int kk = kh*4 + kq;
    int mbase = kk*32 + (l>>4)*8;
    short8 sv = *(const short8*)(P + ((size_t)bh*256 + n)*256 + mbase);
    f32x4 ec_lo = *(const f32x4*)(ec_s + mbase);
    f32x4 ec_hi = *(const f32x4*)(ec_s + mbase + 4);
    short8 a_rat;
    #pragma unroll
    for (int j=0;j<4;++j){
      a_rat[j]   = (short)f2bf(bf2f((ushort_t)sv[j])   * er * ec_lo[j]);
      a_rat[j+4] = (short)f2bf(bf2f((ushort_t)sv[j+4]) * er * ec_hi[j]);
    }
    #pragma unroll
    for (int fn=0; fn<4; ++fn){
      int e = fn*16 + lr;
      short8 bv = *(const short8*)(vT  + ((size_t)bh*64 + e)*256 + mbase);
      short8 bg = *(const short8*)(giT + ((size_t)bh*64 + e)*256 + mbase);
      asa[fn] = __builtin_amdgcn_mfma_f32_16x16x32_bf16(sv,    bv, asa[fn],0,0,0);
      ags[fn] = __builtin_amdgcn_mfma_f32_16x16x32_bf16(a_rat, bg, ags[fn],0,0,0);
    }
  }
  if (kh == 1){
    float* rp = &red[rg][l][0];
    #pragma unroll
    for (int fn=0; fn<4; ++fn){
      *(f32x4*)((char*)rp + (((2*fn)   ^ (l&7))*16)) = asa[fn];
      *(f32x4*)((char*)rp + (((2*fn+1) ^ (l&7))*16)) = ags[fn];
    }
  }
  __syncthreads();
  if (kh == 0){
    const float* rp = &red[rg][l][0];
    #pragma unroll
    for (int fn=0; fn<4; ++fn){
      f32x4 oa = *(const f32x4*)((const char*)rp + (((2*fn)   ^ (l&7))*16));
      f32x4 og = *(const f32x4*)((const char*)rp + (((2*fn+1) ^ (l&7))*16));
      asa[fn] += oa; ags[fn] += og;
    }
    #pragma unroll
    for (int r=0; r<4; ++r){
      int nr = n0 + rg*16 + (l>>4)*4 + r;
      float rinv = 1.0f / rsumb[bh*256 + nr];
      #pragma unroll
      for (int fn=0; fn<4; ++fn){
        int e = fn*16 + lr;
        saf[((size_t)(b*256 + nr))*768 + h*64 + e] = asa[fn][r] * rinv;
        gsb[((size_t)bh*256 + nr)*64 + e] = f2bf(ags[fn][r]);
      }
    }
  }
}

// ---------------------------------------------------------------------------
// K4 v3: K-split x4; partials -> isap[s]
__global__ __launch_bounds__(256) void k_isa(
    const ushort_t* __restrict__ lib, const ushort_t* __restrict__ gib,
    const ushort_t* __restrict__ gsb, const ushort_t* __restrict__ wgb,
    float* __restrict__ isap)
{
  __shared__ char smem[32768];   // 2 x 16KB granule buffers
  const int t = threadIdx.x, w = t>>6, l = t&63;
  const int lr = l&15, lk = l>>4;          // lk in 0..3
  const int t0 = blockIdx.x*128 + w*32;    // wave's first token
  const int s  = blockIdx.y;               // K-split 0..3
  const int d0 = s*16;
  const int inrow = lk*16;

  float  gif[2][2][8];
  short8 gsf[2][2];
  #pragma unroll
  for (int mt=0; mt<2; ++mt){
    #pragma unroll
    for (int ck=0; ck<2; ++ck){
      const size_t rowoff = (size_t)(t0 + mt*16 + lr)*64 + ck*32 + lk*8;
      short8 gv = *(const short8*)(gib + rowoff);
      #pragma unroll
      for (int j=0;j<8;++j) gif[mt][ck][j] = bf2f((ushort_t)gv[j]);
      gsf[mt][ck] = *(const short8*)(gsb + rowoff);
    }
  }
  const size_t liRow0 = (size_t)(t0 +      lr)*64 + d0;
  const size_t liRow1 = (size_t)(t0 + 16 + lr)*64 + d0;

  f32x4 acc[2][4];
  #pragma unroll
  for (int mt=0; mt<2; ++mt)
    #pragma unroll
    for (int et=0; et<4; ++et) acc[mt][et] = (f32x4){0,0,0,0};

  const char* wbase = (const char*)wgb + (size_t)d0*8192;
  short8 stg[4];
  {
    #pragma unroll
    for (int i=0;i<4;++i) stg[i] = *(const short8*)(wbase + (i*256 + t)*16);
    #pragma unroll
    for (int i=0;i<4;++i){
      int L = (i*256 + t)*16, R = L>>7, WB = L&127;
      *(short8*)(smem + R*128 + (WB ^ ((R&7)<<4))) = stg[i];
    }
  }
  __syncthreads();

  for (int g=0; g<8; ++g){
    const char* src = wbase + (size_t)(g+1)*16384;
    #pragma unroll
    for (int i=0;i<4;++i) stg[i] = *(const short8*)(src + (i*256 + t)*16);

    const char* buf = smem + (g&1)*16384;
    #pragma unroll
    for (int dd=0; dd<2; ++dd){
      const int d = g*2 + dd;
      short8 bfr[4][2];
      #pragma unroll
      for (int et=0; et<4; ++et){
        const int e = et*16 + lr;
        const int swz = (e&7)<<4;
        #pragma unroll
        for (int ck=0; ck<2; ++ck)
          bfr[et][ck] = *(const short8*)(buf + dd*8192 + e*128 + ((ck*64 + inrow) ^ swz));
      }
      const float lv0 = bf2f(lib[liRow0 + d]);
      const float lv1 = bf2f(lib[liRow1 + d]);
      short8 au0[2], au1[2];
      #pragma unroll
      for (int ck=0; ck<2; ++ck){
        au0[ck] = mulpack8(gif[0][ck], lv0);
        au1[ck] = mulpack8(gif[1][ck], lv1);
      }
      #pragma unroll
      for (int ck=0; ck<2; ++ck)
        #pragma unroll
        for (int et=0; et<4; ++et){
          acc[0][et] = __builtin_amdgcn_mfma_f32_16x16x32_bf16(au0[ck], bfr[et][ck], acc[0][et],0,0,0);
          acc[1][et] = __builtin_amdgcn_mfma_f32_16x16x32_bf16(au1[ck], bfr[et][ck], acc[1][et],0,0,0);
        }
    }

    char* dbuf = smem + ((g+1)&1)*16384;
    #pragma unroll
    for (int i=0;i<4;++i){
      int L = (i*256 + t)*16, R = L>>7, WB = L&127;
      *(short8*)(dbuf + R*128 + (WB ^ ((R&7)<<4))) = stg[i];
    }
    __syncthreads();
  }

  if (s == 3){
    const char* buf = smem;
    #pragma unroll
    for (int et=0; et<4; ++et){
      const int e = et*16 + lr;
      const int swz = (e&7)<<4;
      #pragma unroll
      for (int ck=0; ck<2; ++ck){
        short8 bfr = *(const short8*)(buf + e*128 + ((ck*64 + inrow) ^ swz));
        acc[0][et] = __builtin_amdgcn_mfma_f32_16x16x32_bf16(gsf[0][ck], bfr, acc[0][et],0,0,0);
        acc[1][et] = __builtin_amdgcn_mfma_f32_16x16x32_bf16(gsf[1][ck], bfr, acc[1][et],0,0,0);
      }
    }
  }

  float* dst = isap + (size_t)s*TOK*768;
  #pragma unroll
  for (int mt=0; mt<2; ++mt){
    #pragma unroll
    for (int et=0; et<4; ++et){
      #pragma unroll
      for (int r=0; r<4; ++r){
        int tok = t0 + mt*16 + lk*4 + r;
        int e = et*16 + lr;
        int bh = tok>>8, n = tok&255;
        int b = bh/12, h = bh - b*12;
        dst[((size_t)(b*256 + n))*768 + h*64 + e] = acc[mt][et][r];
      }
    }
  }
}

// ---------------------------------------------------------------------------
// K5: per-token LayerNorm(sa), LayerNorm(sum of isa partials), gated mix -> zb
__global__ __launch_bounds__(256) void k_lnmix(
    const float* __restrict__ saf, const float* __restrict__ isap,
    const float* __restrict__ lam, ushort_t* __restrict__ zb)
{
  int tok = blockIdx.x*4 + (threadIdx.x>>6);
  int l = threadIdx.x & 63;
  float g = 1.f/(1.f + __expf(-lam[0]));
  const float* sp = saf  + (size_t)tok*768;
  const float* p0 = isap + (size_t)tok*768;
  const float* p1 = p0 + (size_t)TOK*768;
  const float* p2 = p1 + (size_t)TOK*768;
  const float* p3 = p2 + (size_t)TOK*768;
  float sv[12], iv[12];
  float s1=0.f, s2=0.f, i1=0.f, i2=0.f;
  #pragma unroll
  for (int j=0;j<12;++j){
    int o = l + j*64;
    sv[j] = sp[o];  s1 += sv[j];  s2 += sv[j]*sv[j];
    iv[j] = (p0[o] + p1[o]) + (p2[o] + p3[o]);
    i1 += iv[j];  i2 += iv[j]*iv[j];
  }
  #pragma unroll
  for (int m=1; m<64; m<<=1){
    s1 += __shfl_xor(s1, m); s2 += __shfl_xor(s2, m);
    i1 += __shfl_xor(i1, m); i2 += __shfl_xor(i2, m);
  }
  float smean = s1*(1.f/768.f), svar = s2*(1.f/768.f) - smean*smean;
  float imean = i1*(1.f/768.f), ivar = i2*(1.f/768.f) - imean*imean;
  float sinv = 1.f/sqrtf(svar + 1e-5f);
  float iinv = 1.f/sqrtf(ivar + 1e-5f);
  #pragma unroll
  for (int j=0;j<12;++j){
    float z = g*(sv[j]-smean)*sinv + (1.f-g)*(iv[j]-imean)*iinv;
    zb[(size_t)tok*768 + l + j*64] = f2bf(z);
  }
}

// ---------------------------------------------------------------------------
// K6 v2: out = zb @ wpb^T + b_proj (all-bf16, glds16+swizzle, 64^2 tile)
__global__ __launch_bounds__(256) void k_outproj(
    const ushort_t* __restrict__ zb, const ushort_t* __restrict__ wpb,
    const float* __restrict__ bproj, float* __restrict__ out)
{
  __shared__ ushort_t As[64*32];
  __shared__ ushort_t Bs[64*32];
  const int n0 = blockIdx.x*64;
  const int m0 = blockIdx.y*64;
  const int t = threadIdx.x, w = t>>6, l = t&63;
  const int wr = w>>1, wc = w&1;
  const int lr = l&15, lk = l>>4;
  const int srow = w*16 + (l>>2);
  const int scol = ((l&3) ^ ((l>>3)&3)) << 3;
  const int sw = (lr>>1)&3;
  const int rdoff = (lk ^ sw)<<3;
  f32x4 acc00={0,0,0,0}, acc01={0,0,0,0}, acc10={0,0,0,0}, acc11={0,0,0,0};

  for (int k0=0; k0<768; k0+=32){
    glds16(zb  + (size_t)(m0+srow)*768 + k0 + scol, As + w*512);
    glds16(wpb + (size_t)(n0+srow)*768 + k0 + scol, Bs + w*512);
    __syncthreads();
    short8 a0 = *(const short8*)(As + (wr*32 +      lr)*32 + rdoff);
    short8 a1 = *(const short8*)(As + (wr*32 + 16 + lr)*32 + rdoff);
    short8 b0 = *(const short8*)(Bs + (wc*32 +      lr)*32 + rdoff);
    short8 b1 = *(const short8*)(Bs + (wc*32 + 16 + lr)*32 + rdoff);
    acc00 = __builtin_amdgcn_mfma_f32_16x16x32_bf16(a0,b0,acc00,0,0,0);
    acc01 = __builtin_amdgcn_mfma_f32_16x16x32_bf16(a0,b1,acc01,0,0,0);
    acc10 = __builtin_amdgcn_mfma_f32_16x16x32_bf16(a1,b0,acc10,0,0,0);
    acc11 = __builtin_amdgcn_mfma_f32_16x16x32_bf16(a1,b1,acc11,0,0,0);
    __syncthreads();
  }

  #pragma unroll
  for (int fm=0; fm<2; ++fm){
    #pragma unroll
    for (int fn=0; fn<2; ++fn){
      f32x4 acc = (fm==0) ? ((fn==0)?acc00:acc01) : ((fn==0)?acc10:acc11);
      #pragma unroll
      for (int r=0; r<4; ++r){
        int grow = m0 + wr*32 + fm*16 + lk*4 + r;
        int gcol = n0 + wc*32 + fn*16 + lr;
        out[(size_t)grow*768 + gcol] = acc[r] + bproj[gcol];
      }
    }
  }
}

// ---------------------------------------------------------------------------
extern "C" void kernel_launch(void* const* d_in, const int* in_sizes, int n_in,
                              void* d_out, int out_size, void* d_ws, size_t ws_size,
                              hipStream_t stream)
{
  const float* x        = (const float*)d_in[0];
  const float* w_qkv    = (const float*)d_in[1];
  const float* b_qkv    = (const float*)d_in[2];
  const float* w_g      = (const float*)d_in[3];
  const float* w_bg     = (const float*)d_in[4];
  const float* w_local  = (const float*)d_in[5];
  const float* b_local  = (const float*)d_in[6];
  const float* w_globalp= (const float*)d_in[7];
  const float* b_globalp= (const float*)d_in[8];
  const float* lam      = (const float*)d_in[9];
  const float* w_proj   = (const float*)d_in[10];
  const float* b_proj   = (const float*)d_in[11];
  float* out = (float*)d_out;

  char* p = (char*)d_ws;
  auto alloc = [&](size_t bytes)->char*{
    char* r = p; p += (bytes + 255) & ~(size_t)255; return r;
  };
  ushort_t* wgb = (ushort_t*)alloc((size_t)72*4096*2);  // 65 used + prefetch pad
  ushort_t* qb  = (ushort_t*)alloc((size_t)THW*64*2);
  ushort_t* kb  = (ushort_t*)alloc((size_t)THW*64*2);
  ushort_t* vT  = (ushort_t*)alloc((size_t)THW*64*2);
  ushort_t* giT = (ushort_t*)alloc((size_t)THW*64*2);
  ushort_t* gib = (ushort_t*)alloc((size_t)THW*64*2);
  ushort_t* lib = (ushort_t*)alloc((size_t)THW*64*2);
  ushort_t* gsb = (ushort_t*)alloc((size_t)THW*64*2);
  char*   Sreg  = alloc((size_t)BH*256*256*4);          // 25.17 MB region
  float*  rmaxb = (float*)  alloc((size_t)BH*256*4);
  float*  rsumb = (float*)  alloc((size_t)BH*256*4);
  float*  colpm = (float*)  alloc((size_t)BH*8*256*4);
  float*  colps = (float*)  alloc((size_t)BH*8*256*4);
  ushort_t* wpb = (ushort_t*)alloc((size_t)768*768*2);    // bf16 w_proj
  // Aliases over dead buffers:
  ushort_t* P16  = (ushort_t*)Sreg; // 12.6 MB bf16 P (dead after k_attnmm)
  float*    saf  = (float*)qb;      // over qb+kb (dead after k_logits)
  ushort_t* zb   = (ushort_t*)gsb;  // over gsb (dead after k_isa)
  float*    isap = (float*)Sreg;    // 4 partials over S region
  ushort_t* xb   = (ushort_t*)Sreg;                   // dead after k_proj
  ushort_t* wb   = (ushort_t*)Sreg + (size_t)TOK*768; // dead after k_proj

  hipLaunchKernelGGL(k_pack, dim3(2626), dim3(256), 0, stream,
                     x, w_qkv, w_local, w_globalp, w_proj, w_g, w_bg,
                     xb, wb, wpb, wgb);
  hipLaunchKernelGGL(k_proj, dim3(60,16), dim3(256), 0, stream,
                     xb, wb, b_qkv, b_local, b_globalp,
                     qb, kb, vT, lib, gib, giT);
  hipLaunchKernelGGL(k_logits, dim3(96,8), dim3(256), 0, stream,
                     qb, kb, P16, rmaxb, rsumb, colpm, colps);
  hipLaunchKernelGGL(k_attnmm, dim3(96,8), dim3(256), 0, stream,
                     P16, rmaxb, rsumb, colpm, colps, vT, giT, gsb, saf);
  hipLaunchKernelGGL(k_isa, dim3(192,4), dim3(256), 0, stream,
                     lib, gib, gsb, wgb, isap);
  hipLaunchKernelGGL(k_lnmix, dim3(512), dim3(256), 0, stream,
                     saf, isap, lam, zb);
  hipLaunchKernelGGL(k_outproj, dim3(12,32), dim3(256), 0, stream,
                     zb, wpb, b_proj, out);
}

// Round 19
// 108.761 us; speedup vs baseline: 1.2005x; 1.0115x over previous
//
#include <hip/hip_runtime.h>
#include <hip/hip_bf16.h>

// Problem constants
#define BH 96      // B*H
#define TOK 2048   // B*N
#define THW 24576  // B*H*N

typedef unsigned short ushort_t;
typedef __attribute__((ext_vector_type(8))) short short8;
typedef __attribute__((ext_vector_type(4))) short short4_t;
typedef __attribute__((ext_vector_type(4))) float f32x4;

static __device__ __forceinline__ float bf2f(ushort_t u){
  union { unsigned int i; float f; } t; t.i = ((unsigned int)u)<<16; return t.f;
}
static __device__ __forceinline__ ushort_t f2bf(float f){
  union { float f; unsigned int i; } t; t.f = f;
  unsigned int u = t.i;
  return (ushort_t)((u + 0x7fffu + ((u>>16)&1u)) >> 16);
}
static __device__ __forceinline__ short8 pack8(f32x4 a, f32x4 b){
  short8 r;
  #pragma unroll
  for (int j=0;j<4;++j){ r[j]=(short)f2bf(a[j]); r[4+j]=(short)f2bf(b[j]); }
  return r;
}
static __device__ __forceinline__ float gelu_exact(float x){
  return 0.5f*x*(1.0f + erff(x*0.70710678118654752f));
}
// 8 f32 scaled by s -> bf16x8 (RNE via v_cvt_pk_bf16_f32)
static __device__ __forceinline__ short8 mulpack8(const float* f, float s){
  union { short8 s8; unsigned int u[4]; } r;
  #pragma unroll
  for (int j=0;j<4;++j){
    float2 p2; p2.x = f[2*j]*s; p2.y = f[2*j+1]*s;
    __hip_bfloat162 p = __float22bfloat162_rn(p2);
    r.u[j] = *(unsigned int*)&p;
  }
  return r.s8;
}
// async global->LDS, 16B per lane; LDS dest = uniform base + lane*16
static __device__ __forceinline__ void glds16(const ushort_t* g, ushort_t* l){
  __builtin_amdgcn_global_load_lds(
      (const __attribute__((address_space(1))) unsigned int*)g,
      (__attribute__((address_space(3))) unsigned int*)l, 16, 0, 0);
}

// ---------------------------------------------------------------------------
// K0: unified bf16 pack.
__global__ __launch_bounds__(256) void k_pack(
    const float* __restrict__ x, const float* __restrict__ w_qkv,
    const float* __restrict__ w_local, const float* __restrict__ w_global,
    const float* __restrict__ w_proj, const float* __restrict__ w_g,
    const float* __restrict__ w_bg,
    ushort_t* __restrict__ xb, ushort_t* __restrict__ wb,
    ushort_t* __restrict__ wpb, ushort_t* __restrict__ wgb)
{
  size_t i = ((size_t)blockIdx.x*256 + threadIdx.x)*8;
  const float* src; ushort_t* dst; size_t off;
  if (i < 1572864){ src = x; dst = xb; off = i; }
  else if (i < 4521984){
    size_t j = i - 1572864; dst = wb; off = j;
    if (j < 1769472)      src = w_qkv;
    else if (j < 2359296) src = w_local - 1769472;
    else                  src = w_global - 2359296;
  }
  else if (i < 5111808){ off = i - 4521984; src = w_proj; dst = wpb; }
  else {
    size_t j = i - 5111808; dst = wgb; off = j;
    src = (j < 262144) ? w_g : (w_bg - 262144);
  }
  f32x4 a = *(const f32x4*)(src + off);
  f32x4 b = *(const f32x4*)(src + off + 4);
  *(short8*)(dst + off) = pack8(a, b);
}

// ---------------------------------------------------------------------------
// K1 v5: 128x64 tile, BK=64, single-buffer 24KB; epilogue writes vT/giT
// directly (transposed packed 8B stores).
__global__ __launch_bounds__(256) void k_proj(
    const ushort_t* __restrict__ xb, const ushort_t* __restrict__ wb,
    const float* __restrict__ b_qkv, const float* __restrict__ b_local,
    const float* __restrict__ b_global,
    ushort_t* __restrict__ qb, ushort_t* __restrict__ kb,
    ushort_t* __restrict__ vT, ushort_t* __restrict__ lib,
    ushort_t* __restrict__ gib, ushort_t* __restrict__ giT)
{
  __shared__ ushort_t As[128*64];   // 16 KB
  __shared__ ushort_t Bs[64*64];    //  8 KB
  const int n0 = blockIdx.x*64;
  const int m0 = blockIdx.y*128;
  const int t = threadIdx.x, w = t>>6, l = t&63;
  const int wm = (w>>1)*64, wn = (w&1)*32;
  const int lr = l&15, lk = l>>4;               // lk 0..3
  const int sgrow = l>>3;                       // 0..7
  const int sgcol = ((l&7) ^ (l>>3))*8;         // inverse-swizzled elem col
  f32x4 acc[4][2];
  #pragma unroll
  for (int a=0;a<4;++a){ acc[a][0]=(f32x4){0,0,0,0}; acc[a][1]=(f32x4){0,0,0,0}; }

  for (int k0=0; k0<768; k0+=64){
    #pragma unroll
    for (int pp=0; pp<4; ++pp){
      int r0 = w*32 + pp*8;
      glds16(xb + (size_t)(m0+r0+sgrow)*768 + k0 + sgcol, As + r0*64);
    }
    #pragma unroll
    for (int pp=0; pp<2; ++pp){
      int r0 = w*16 + pp*8;
      glds16(wb + (size_t)(n0+r0+sgrow)*768 + k0 + sgcol, Bs + r0*64);
    }
    __syncthreads();
    short8 af[2][4], bf[2][2];
    #pragma unroll
    for (int kk=0; kk<2; ++kk){
      #pragma unroll
      for (int fm=0; fm<4; ++fm){
        int R = wm + fm*16 + lr;
        af[kk][fm] = *(const short8*)(As + R*64 + (((4*kk+lk) ^ (lr&7))*8));
      }
      #pragma unroll
      for (int fn=0; fn<2; ++fn){
        int R = wn + fn*16 + lr;
        bf[kk][fn] = *(const short8*)(Bs + R*64 + (((4*kk+lk) ^ (lr&7))*8));
      }
    }
    #pragma unroll
    for (int kk=0; kk<2; ++kk)
      #pragma unroll
      for (int fm=0; fm<4; ++fm)
        #pragma unroll
        for (int fn=0; fn<2; ++fn)
          acc[fm][fn] = __builtin_amdgcn_mfma_f32_16x16x32_bf16(af[kk][fm], bf[kk][fn], acc[fm][fn],0,0,0);
    __syncthreads();
  }

  #pragma unroll
  for (int fm=0; fm<4; ++fm){
    #pragma unroll
    for (int fn=0; fn<2; ++fn){
      const int grow0 = m0 + wm + fm*16 + lk*4;   // first of 4 consecutive rows
      const int colg  = n0 + wn + fn*16 + lr;
      const int b = grow0>>8, nloc = grow0&255;   // 4 rows stay in-batch (128|m0)
      if (colg < 1536){
        #pragma unroll
        for (int r=0; r<4; ++r){
          float val = acc[fm][fn][r] + b_qkv[colg];
          int h = (colg - ((colg<768)?0:768))>>6, d = colg&63;
          size_t idx = ((size_t)(b*12+h)*256 + nloc + r)*64 + d;
          if (colg < 768) qb[idx] = f2bf(val*0.125f);
          else            kb[idx] = f2bf(val);
        }
      } else if (colg < 2304){
        int rr = colg - 1536;
        int h = rr>>6, d = rr&63;
        short4_t pk;
        #pragma unroll
        for (int r=0; r<4; ++r)
          pk[r] = (short)f2bf(acc[fm][fn][r] + b_qkv[colg]);
        *(short4_t*)(vT + ((size_t)(b*12+h)*64 + d)*256 + nloc) = pk;
      } else if (colg < 3072){
        int cl = colg - 2304;
        int h = cl>>6, d = cl&63;
        #pragma unroll
        for (int r=0; r<4; ++r){
          float val = acc[fm][fn][r] + b_local[cl];
          lib[((size_t)(b*12+h)*256 + nloc + r)*64 + d] = f2bf(gelu_exact(val));
        }
      } else {
        int cl = colg - 3072;
        int h = cl>>6, d = cl&63;
        short4_t pk;
        #pragma unroll
        for (int r=0; r<4; ++r){
          float gv = gelu_exact(acc[fm][fn][r] + b_global[cl]);
          ushort_t gb = f2bf(gv);
          gib[((size_t)(b*12+h)*256 + nloc + r)*64 + d] = gb;
          pk[r] = (short)gb;
        }
        *(short4_t*)(giT + ((size_t)(b*12+h)*64 + d)*256 + nloc) = pk;
      }
    }
  }
}

// ---------------------------------------------------------------------------
// K3a v5: col-split x2; stores P = exp(s - rmax_full) in bf16.
__global__ __launch_bounds__(256) void k_logits(
    const ushort_t* __restrict__ qb, const ushort_t* __restrict__ kb,
    ushort_t* __restrict__ P, float* __restrict__ rmaxb, float* __restrict__ rsumb,
    float* __restrict__ colpm, float* __restrict__ colps)
{
  __shared__ float lpm[2][256], lps[2][256];   // [rg][ch*128+col]
  __shared__ float rpm[2][32], rps[2][32];     // [ch][row-in-block]
  __shared__ float rmax_s[32];
  int bh = blockIdx.x, n0 = blockIdx.y*32;
  int t = threadIdx.x, w = t>>6, l = t&63;
  int rg = w&1, ch = w>>1;
  int lr = l&15, lk = (l>>4)*8;
  int row = n0 + rg*16 + lr;
  const ushort_t* qp = qb + ((size_t)bh*256 + row)*64 + lk;
  short8 a0 = *(const short8*)(qp);
  short8 a1 = *(const short8*)(qp + 32);
  f32x4 acc[8];
  #pragma unroll
  for (int f=0; f<8; ++f) acc[f] = (f32x4){0,0,0,0};
  #pragma unroll
  for (int f=0; f<8; ++f){
    int col = ch*128 + f*16 + lr;
    const ushort_t* kp = kb + ((size_t)bh*256 + col)*64 + lk;
    short8 b0 = *(const short8*)(kp);
    short8 b1 = *(const short8*)(kp + 32);
    acc[f] = __builtin_amdgcn_mfma_f32_16x16x32_bf16(a0,b0,acc[f],0,0,0);
    acc[f] = __builtin_amdgcn_mfma_f32_16x16x32_bf16(a1,b1,acc[f],0,0,0);
  }
  // row partial stats; keep e = exp(acc - mx_part) in registers
  f32x4 e[8];
  float mxp[4];
  #pragma unroll
  for (int r=0; r<4; ++r){
    int nl = rg*16 + (l>>4)*4 + r;            // row within block
    float mx = acc[0][r];
    #pragma unroll
    for (int f=1; f<8; ++f) mx = fmaxf(mx, acc[f][r]);
    mx = fmaxf(mx, __shfl_xor(mx, 1));
    mx = fmaxf(mx, __shfl_xor(mx, 2));
    mx = fmaxf(mx, __shfl_xor(mx, 4));
    mx = fmaxf(mx, __shfl_xor(mx, 8));
    mxp[r] = mx;
    float sm = 0.f;
    #pragma unroll
    for (int f=0; f<8; ++f){ e[f][r] = __expf(acc[f][r] - mx); sm += e[f][r]; }
    sm += __shfl_xor(sm, 1);
    sm += __shfl_xor(sm, 2);
    sm += __shfl_xor(sm, 4);
    sm += __shfl_xor(sm, 8);
    if (lr == 0){ rpm[ch][nl] = mx; rps[ch][nl] = sm; }
  }
  // col partials (raw s)
  #pragma unroll
  for (int f=0; f<8; ++f){
    float pm = fmaxf(fmaxf(acc[f][0],acc[f][1]), fmaxf(acc[f][2],acc[f][3]));
    float ps = __expf(acc[f][0]-pm) + __expf(acc[f][1]-pm)
             + __expf(acc[f][2]-pm) + __expf(acc[f][3]-pm);
    #pragma unroll
    for (int m=16; m<64; m<<=1){
      float om = __shfl_xor(pm, m);
      float os = __shfl_xor(ps, m);
      float nm = fmaxf(pm, om);
      ps = ps*__expf(pm-nm) + os*__expf(om-nm);
      pm = nm;
    }
    if (l < 16){ lpm[rg][ch*128 + f*16 + lr] = pm; lps[rg][ch*128 + f*16 + lr] = ps; }
  }
  __syncthreads();
  if (t < 32){
    float M = rpm[0][t], Sm = rps[0][t];
    float om = rpm[1][t], os = rps[1][t];
    float nm = fmaxf(M, om);
    Sm = Sm*__expf(M-nm) + os*__expf(om-nm);
    rmaxb[bh*256 + n0 + t] = nm;
    rsumb[bh*256 + n0 + t] = Sm;
    rmax_s[t] = nm;
  }
  {
    float M = lpm[0][t], Sm = lps[0][t];
    float om = lpm[1][t], os = lps[1][t];
    float nm = fmaxf(M, om);
    Sm = Sm*__expf(M-nm) + os*__expf(om-nm);
    colpm[((size_t)bh*8 + blockIdx.y)*256 + t] = nm;
    colps[((size_t)bh*8 + blockIdx.y)*256 + t] = Sm;
  }
  __syncthreads();
  // P store: rescale partial exps by exp(mx_part - rmax_full)
  #pragma unroll
  for (int r=0; r<4; ++r){
    int nl = rg*16 + (l>>4)*4 + r;
    float sc = __expf(mxp[r] - rmax_s[nl]);
    #pragma unroll
    for (int f=0; f<8; ++f)
      P[((size_t)bh*256 + n0 + nl)*256 + ch*128 + f*16 + lr] = f2bf(e[f][r]*sc);
  }
}

// ---------------------------------------------------------------------------
// K3c v5: A-fragments from stored P — a_at = P verbatim; a_rat = P*er*ec.
__global__ __launch_bounds__(256) void k_attnmm(
    const ushort_t* __restrict__ P,
    const float* __restrict__ rmaxb, const float* __restrict__ rsumb,
    const float* __restrict__ colpm, const float* __restrict__ colps,
    const ushort_t* __restrict__ vT, const ushort_t* __restrict__ giT,
    ushort_t* __restrict__ gsb, float* __restrict__ saf)
{
  __shared__ float ec_s[256];
  __shared__ float red[2][64][32];   // [rg][lane][8 x f32x4], XOR-swizzled
  int bh = blockIdx.x, n0 = blockIdx.y*32;
  int b = bh/12, h = bh - b*12;
  int t = threadIdx.x, w = t>>6, l = t&63;
  int rg = w&1, kh = w>>1;
  int lr = l&15;
  {
    const float* pm = colpm + (size_t)bh*2048;
    const float* ps = colps + (size_t)bh*2048;
    float M = pm[t], Ssum = ps[t];
    #pragma unroll
    for (int k=1; k<8; ++k){
      float om = pm[k*256+t], os = ps[k*256+t];
      float nm = fmaxf(M, om);
      Ssum = Ssum*__expf(M-nm) + os*__expf(om-nm);
      M = nm;
    }
    ec_s[t] = __expf(-M)/Ssum;
  }
  __syncthreads();
  int n = n0 + rg*16 + lr;   // A-fragment row
  float er = __expf(rmaxb[bh*256 + n]);
  f32x4 asa[4], ags[4];
  #pragma unroll
  for (int fn=0; fn<4; ++fn){ asa[fn]=(f32x4){0,0,0,0}; ags[fn]=(f32x4){0,0,0,0}; }
  #pragma unroll
  for (int kq=0; kq<4; ++kq){
    int kk = kh*4 + kq;
    int mbase = kk*32 + (l>>4)*8;
    short8 sv = *(const short8*)(P + ((size_t)bh*256 + n)*256 + mbase);
    f32x4 ec_lo = *(const f32x4*)(ec_s + mbase);
    f32x4 ec_hi = *(const f32x4*)(ec_s + mbase + 4);
    short8 a_rat;
    #pragma unroll
    for (int j=0;j<4;++j){
      a_rat[j]   = (short)f2bf(bf2f((ushort_t)sv[j])   * er * ec_lo[j]);
      a_rat[j+4] = (short)f2bf(bf2f((ushort_t)sv[j+4]) * er * ec_hi[j]);
    }
    #pragma unroll
    for (int fn=0; fn<4; ++fn){
      int e = fn*16 + lr;
      short8 bv = *(const short8*)(vT  + ((size_t)bh*64 + e)*256 + mbase);
      short8 bg = *(const short8*)(giT + ((size_t)bh*64 + e)*256 + mbase);
      asa[fn] = __builtin_amdgcn_mfma_f32_16x16x32_bf16(sv,    bv, asa[fn],0,0,0);
      ags[fn] = __builtin_amdgcn_mfma_f32_16x16x32_bf16(a_rat, bg, ags[fn],0,0,0);
    }
  }
  if (kh == 1){
    float* rp = &red[rg][l][0];
    #pragma unroll
    for (int fn=0; fn<4; ++fn){
      *(f32x4*)((char*)rp + (((2*fn)   ^ (l&7))*16)) = asa[fn];
      *(f32x4*)((char*)rp + (((2*fn+1) ^ (l&7))*16)) = ags[fn];
    }
  }
  __syncthreads();
  if (kh == 0){
    const float* rp = &red[rg][l][0];
    #pragma unroll
    for (int fn=0; fn<4; ++fn){
      f32x4 oa = *(const f32x4*)((const char*)rp + (((2*fn)   ^ (l&7))*16));
      f32x4 og = *(const f32x4*)((const char*)rp + (((2*fn+1) ^ (l&7))*16));
      asa[fn] += oa; ags[fn] += og;
    }
    #pragma unroll
    for (int r=0; r<4; ++r){
      int nr = n0 + rg*16 + (l>>4)*4 + r;
      float rinv = 1.0f / rsumb[bh*256 + nr];
      #pragma unroll
      for (int fn=0; fn<4; ++fn){
        int e = fn*16 + lr;
        saf[((size_t)(b*256 + nr))*768 + h*64 + e] = asa[fn][r] * rinv;
        gsb[((size_t)bh*256 + nr)*64 + e] = f2bf(ags[fn][r]);
      }
    }
  }
}

// ---------------------------------------------------------------------------
// K4 v3: K-split x4; partials -> isap[s]
__global__ __launch_bounds__(256) void k_isa(
    const ushort_t* __restrict__ lib, const ushort_t* __restrict__ gib,
    const ushort_t* __restrict__ gsb, const ushort_t* __restrict__ wgb,
    float* __restrict__ isap)
{
  __shared__ char smem[32768];   // 2 x 16KB granule buffers
  const int t = threadIdx.x, w = t>>6, l = t&63;
  const int lr = l&15, lk = l>>4;          // lk in 0..3
  const int t0 = blockIdx.x*128 + w*32;    // wave's first token
  const int s  = blockIdx.y;               // K-split 0..3
  const int d0 = s*16;
  const int inrow = lk*16;

  float  gif[2][2][8];
  short8 gsf[2][2];
  #pragma unroll
  for (int mt=0; mt<2; ++mt){
    #pragma unroll
    for (int ck=0; ck<2; ++ck){
      const size_t rowoff = (size_t)(t0 + mt*16 + lr)*64 + ck*32 + lk*8;
      short8 gv = *(const short8*)(gib + rowoff);
      #pragma unroll
      for (int j=0;j<8;++j) gif[mt][ck][j] = bf2f((ushort_t)gv[j]);
      gsf[mt][ck] = *(const short8*)(gsb + rowoff);
    }
  }
  const size_t liRow0 = (size_t)(t0 +      lr)*64 + d0;
  const size_t liRow1 = (size_t)(t0 + 16 + lr)*64 + d0;

  f32x4 acc[2][4];
  #pragma unroll
  for (int mt=0; mt<2; ++mt)
    #pragma unroll
    for (int et=0; et<4; ++et) acc[mt][et] = (f32x4){0,0,0,0};

  const char* wbase = (const char*)wgb + (size_t)d0*8192;
  short8 stg[4];
  {
    #pragma unroll
    for (int i=0;i<4;++i) stg[i] = *(const short8*)(wbase + (i*256 + t)*16);
    #pragma unroll
    for (int i=0;i<4;++i){
      int L = (i*256 + t)*16, R = L>>7, WB = L&127;
      *(short8*)(smem + R*128 + (WB ^ ((R&7)<<4))) = stg[i];
    }
  }
  __syncthreads();

  for (int g=0; g<8; ++g){
    const char* src = wbase + (size_t)(g+1)*16384;
    #pragma unroll
    for (int i=0;i<4;++i) stg[i] = *(const short8*)(src + (i*256 + t)*16);

    const char* buf = smem + (g&1)*16384;
    #pragma unroll
    for (int dd=0; dd<2; ++dd){
      const int d = g*2 + dd;
      short8 bfr[4][2];
      #pragma unroll
      for (int et=0; et<4; ++et){
        const int e = et*16 + lr;
        const int swz = (e&7)<<4;
        #pragma unroll
        for (int ck=0; ck<2; ++ck)
          bfr[et][ck] = *(const short8*)(buf + dd*8192 + e*128 + ((ck*64 + inrow) ^ swz));
      }
      const float lv0 = bf2f(lib[liRow0 + d]);
      const float lv1 = bf2f(lib[liRow1 + d]);
      short8 au0[2], au1[2];
      #pragma unroll
      for (int ck=0; ck<2; ++ck){
        au0[ck] = mulpack8(gif[0][ck], lv0);
        au1[ck] = mulpack8(gif[1][ck], lv1);
      }
      #pragma unroll
      for (int ck=0; ck<2; ++ck)
        #pragma unroll
        for (int et=0; et<4; ++et){
          acc[0][et] = __builtin_amdgcn_mfma_f32_16x16x32_bf16(au0[ck], bfr[et][ck], acc[0][et],0,0,0);
          acc[1][et] = __builtin_amdgcn_mfma_f32_16x16x32_bf16(au1[ck], bfr[et][ck], acc[1][et],0,0,0);
        }
    }

    char* dbuf = smem + ((g+1)&1)*16384;
    #pragma unroll
    for (int i=0;i<4;++i){
      int L = (i*256 + t)*16, R = L>>7, WB = L&127;
      *(short8*)(dbuf + R*128 + (WB ^ ((R&7)<<4))) = stg[i];
    }
    __syncthreads();
  }

  if (s == 3){
    const char* buf = smem;
    #pragma unroll
    for (int et=0; et<4; ++et){
      const int e = et*16 + lr;
      const int swz = (e&7)<<4;
      #pragma unroll
      for (int ck=0; ck<2; ++ck){
        short8 bfr = *(const short8*)(buf + e*128 + ((ck*64 + inrow) ^ swz));
        acc[0][et] = __builtin_amdgcn_mfma_f32_16x16x32_bf16(gsf[0][ck], bfr, acc[0][et],0,0,0);
        acc[1][et] = __builtin_amdgcn_mfma_f32_16x16x32_bf16(gsf[1][ck], bfr, acc[1][et],0,0,0);
      }
    }
  }

  float* dst = isap + (size_t)s*TOK*768;
  #pragma unroll
  for (int mt=0; mt<2; ++mt){
    #pragma unroll
    for (int et=0; et<4; ++et){
      #pragma unroll
      for (int r=0; r<4; ++r){
        int tok = t0 + mt*16 + lk*4 + r;
        int e = et*16 + lr;
        int bh = tok>>8, n = tok&255;
        int b = bh/12, h = bh - b*12;
        dst[((size_t)(b*256 + n))*768 + h*64 + e] = acc[mt][et][r];
      }
    }
  }
}

// ---------------------------------------------------------------------------
// K5: per-token LayerNorm(sa), LayerNorm(sum of isa partials), gated mix -> zb
__global__ __launch_bounds__(256) void k_lnmix(
    const float* __restrict__ saf, const float* __restrict__ isap,
    const float* __restrict__ lam, ushort_t* __restrict__ zb)
{
  int tok = blockIdx.x*4 + (threadIdx.x>>6);
  int l = threadIdx.x & 63;
  float g = 1.f/(1.f + __expf(-lam[0]));
  const float* sp = saf  + (size_t)tok*768;
  const float* p0 = isap + (size_t)tok*768;
  const float* p1 = p0 + (size_t)TOK*768;
  const float* p2 = p1 + (size_t)TOK*768;
  const float* p3 = p2 + (size_t)TOK*768;
  float sv[12], iv[12];
  float s1=0.f, s2=0.f, i1=0.f, i2=0.f;
  #pragma unroll
  for (int j=0;j<12;++j){
    int o = l + j*64;
    sv[j] = sp[o];  s1 += sv[j];  s2 += sv[j]*sv[j];
    iv[j] = (p0[o] + p1[o]) + (p2[o] + p3[o]);
    i1 += iv[j];  i2 += iv[j]*iv[j];
  }
  #pragma unroll
  for (int m=1; m<64; m<<=1){
    s1 += __shfl_xor(s1, m); s2 += __shfl_xor(s2, m);
    i1 += __shfl_xor(i1, m); i2 += __shfl_xor(i2, m);
  }
  float smean = s1*(1.f/768.f), svar = s2*(1.f/768.f) - smean*smean;
  float imean = i1*(1.f/768.f), ivar = i2*(1.f/768.f) - imean*imean;
  float sinv = 1.f/sqrtf(svar + 1e-5f);
  float iinv = 1.f/sqrtf(ivar + 1e-5f);
  #pragma unroll
  for (int j=0;j<12;++j){
    float z = g*(sv[j]-smean)*sinv + (1.f-g)*(iv[j]-imean)*iinv;
    zb[(size_t)tok*768 + l + j*64] = f2bf(z);
  }
}

// ---------------------------------------------------------------------------
// K6 v4: out = zb @ wpb^T + b_proj. 32x64 tile, BK=64, grid (12,64)=768
// blocks (3/CU, 2x occupancy), 12 KB LDS, k_proj-v4 staging recipe.
__global__ __launch_bounds__(256) void k_outproj(
    const ushort_t* __restrict__ zb, const ushort_t* __restrict__ wpb,
    const float* __restrict__ bproj, float* __restrict__ out)
{
  __shared__ ushort_t As[32*64];   // 4 KB
  __shared__ ushort_t Bs[64*64];   // 8 KB
  const int n0 = blockIdx.x*64;
  const int m0 = blockIdx.y*32;
  const int t = threadIdx.x, w = t>>6, l = t&63;
  const int wr = w>>1, wc = w&1;              // wr: m-half (16), wc: n-half (32)
  const int lr = l&15, lk = l>>4;
  const int sgrow = l>>3;                     // 0..7
  const int sgcol = ((l&7) ^ (l>>3))*8;       // inverse-swizzled elem col
  f32x4 acc0={0,0,0,0}, acc1={0,0,0,0};

  for (int k0=0; k0<768; k0+=64){
    // A: 32 rows = 4 chunks of 8; wave w stages chunk w
    glds16(zb + (size_t)(m0 + w*8 + sgrow)*768 + k0 + sgcol, As + (w*8)*64);
    // B: 64 rows = 8 chunks; wave w stages chunks 2w, 2w+1
    glds16(wpb + (size_t)(n0 + w*16     + sgrow)*768 + k0 + sgcol, Bs + (w*16    )*64);
    glds16(wpb + (size_t)(n0 + w*16 + 8 + sgrow)*768 + k0 + sgcol, Bs + (w*16 + 8)*64);
    __syncthreads();
    #pragma unroll
    for (int kk=0; kk<2; ++kk){
      const int ro = ((4*kk+lk) ^ (lr&7))*8;
      short8 a0 = *(const short8*)(As + (wr*16 + lr)*64 + ro);
      short8 b0 = *(const short8*)(Bs + (wc*32 +      lr)*64 + ro);
      short8 b1 = *(const short8*)(Bs + (wc*32 + 16 + lr)*64 + ro);
      acc0 = __builtin_amdgcn_mfma_f32_16x16x32_bf16(a0,b0,acc0,0,0,0);
      acc1 = __builtin_amdgcn_mfma_f32_16x16x32_bf16(a0,b1,acc1,0,0,0);
    }
    __syncthreads();
  }

  #pragma unroll
  for (int fn=0; fn<2; ++fn){
    f32x4 acc = fn ? acc1 : acc0;
    #pragma unroll
    for (int r=0; r<4; ++r){
      int grow = m0 + wr*16 + lk*4 + r;
      int gcol = n0 + wc*32 + fn*16 + lr;
      out[(size_t)grow*768 + gcol] = acc[r] + bproj[gcol];
    }
  }
}

// ---------------------------------------------------------------------------
extern "C" void kernel_launch(void* const* d_in, const int* in_sizes, int n_in,
                              void* d_out, int out_size, void* d_ws, size_t ws_size,
                              hipStream_t stream)
{
  const float* x        = (const float*)d_in[0];
  const float* w_qkv    = (const float*)d_in[1];
  const float* b_qkv    = (const float*)d_in[2];
  const float* w_g      = (const float*)d_in[3];
  const float* w_bg     = (const float*)d_in[4];
  const float* w_local  = (const float*)d_in[5];
  const float* b_local  = (const float*)d_in[6];
  const float* w_globalp= (const float*)d_in[7];
  const float* b_globalp= (const float*)d_in[8];
  const float* lam      = (const float*)d_in[9];
  const float* w_proj   = (const float*)d_in[10];
  const float* b_proj   = (const float*)d_in[11];
  float* out = (float*)d_out;

  char* p = (char*)d_ws;
  auto alloc = [&](size_t bytes)->char*{
    char* r = p; p += (bytes + 255) & ~(size_t)255; return r;
  };
  ushort_t* wgb = (ushort_t*)alloc((size_t)72*4096*2);  // 65 used + prefetch pad
  ushort_t* qb  = (ushort_t*)alloc((size_t)THW*64*2);
  ushort_t* kb  = (ushort_t*)alloc((size_t)THW*64*2);
  ushort_t* vT  = (ushort_t*)alloc((size_t)THW*64*2);
  ushort_t* giT = (ushort_t*)alloc((size_t)THW*64*2);
  ushort_t* gib = (ushort_t*)alloc((size_t)THW*64*2);
  ushort_t* lib = (ushort_t*)alloc((size_t)THW*64*2);
  ushort_t* gsb = (ushort_t*)alloc((size_t)THW*64*2);
  char*   Sreg  = alloc((size_t)BH*256*256*4);          // 25.17 MB region
  float*  rmaxb = (float*)  alloc((size_t)BH*256*4);
  float*  rsumb = (float*)  alloc((size_t)BH*256*4);
  float*  colpm = (float*)  alloc((size_t)BH*8*256*4);
  float*  colps = (float*)  alloc((size_t)BH*8*256*4);
  ushort_t* wpb = (ushort_t*)alloc((size_t)768*768*2);    // bf16 w_proj
  // Aliases over dead buffers:
  ushort_t* P16  = (ushort_t*)Sreg; // 12.6 MB bf16 P (dead after k_attnmm)
  float*    saf  = (float*)qb;      // over qb+kb (dead after k_logits)
  ushort_t* zb   = (ushort_t*)gsb;  // over gsb (dead after k_isa)
  float*    isap = (float*)Sreg;    // 4 partials over S region
  ushort_t* xb   = (ushort_t*)Sreg;                   // dead after k_proj
  ushort_t* wb   = (ushort_t*)Sreg + (size_t)TOK*768; // dead after k_proj

  hipLaunchKernelGGL(k_pack, dim3(2626), dim3(256), 0, stream,
                     x, w_qkv, w_local, w_globalp, w_proj, w_g, w_bg,
                     xb, wb, wpb, wgb);
  hipLaunchKernelGGL(k_proj, dim3(60,16), dim3(256), 0, stream,
                     xb, wb, b_qkv, b_local, b_globalp,
                     qb, kb, vT, lib, gib, giT);
  hipLaunchKernelGGL(k_logits, dim3(96,8), dim3(256), 0, stream,
                     qb, kb, P16, rmaxb, rsumb, colpm, colps);
  hipLaunchKernelGGL(k_attnmm, dim3(96,8), dim3(256), 0, stream,
                     P16, rmaxb, rsumb, colpm, colps, vT, giT, gsb, saf);
  hipLaunchKernelGGL(k_isa, dim3(192,4), dim3(256), 0, stream,
                     lib, gib, gsb, wgb, isap);
  hipLaunchKernelGGL(k_lnmix, dim3(512), dim3(256), 0, stream,
                     saf, isap, lam, zb);
  hipLaunchKernelGGL(k_outproj, dim3(12,64), dim3(256), 0, stream,
                     zb, wpb, b_proj, out);
}